// Round 6
// baseline (6963.979 us; speedup 1.0000x reference)
//
#include <hip/hip_runtime.h>
#include <math.h>

#define N_PTS 8192
#define BATCH 4
#define CH 128
#define KNN 20
#define CAP 112
#define QPB 32            // queries per knn block
#define GDIM 40
#define GX0 -5.2f
#define GH 0.26f
#define GINVH (1.0f/0.26f)
#define NCELL (GDIM*GDIM*GDIM)            // 64000 per batch
#define NCELLT (NCELL*BATCH)              // 256000 total

// ======================================================================
// LAPACK ssyevd emulation for 3x3 symmetric (lower), SINGLE precision.
// (verified passing rounds 2-5 — do not perturb numerics)
// ======================================================================

__device__ __forceinline__ float slapy2f(float x, float y) {
#pragma clang fp contract(off)
  float ax = fabsf(x), ay = fabsf(y);
  float w = fmaxf(ax, ay), z = fminf(ax, ay);
  if (z == 0.0f) return w;
  float t = z / w;
  return w * sqrtf(1.0f + t * t);
}

__device__ __forceinline__ void slartgf(float f, float g, float* cs, float* sn, float* r) {
#pragma clang fp contract(off)
  if (g == 0.0f) { *cs = 1.0f; *sn = 0.0f; *r = f; }
  else if (f == 0.0f) { *cs = 0.0f; *sn = copysignf(1.0f, g); *r = fabsf(g); }
  else {
    float f1 = fabsf(f);
    float d = sqrtf(f * f + g * g);
    *cs = f1 / d;
    *r = copysignf(d, f);
    *sn = g / (*r);
  }
}

__device__ void slaev2f(float a, float b, float c, float* rt1, float* rt2,
                        float* cs1, float* sn1) {
#pragma clang fp contract(off)
  float sm = a + c, df = a - c, adf = fabsf(df);
  float tb = b + b, ab = fabsf(tb);
  float acmx, acmn;
  if (fabsf(a) > fabsf(c)) { acmx = a; acmn = c; } else { acmx = c; acmn = a; }
  float rt;
  if (adf > ab)      { float q = ab / adf;  rt = adf * sqrtf(1.0f + q * q); }
  else if (adf < ab) { float q = adf / ab;  rt = ab * sqrtf(1.0f + q * q); }
  else               rt = ab * sqrtf(2.0f);
  int sgn1;
  if (sm < 0.0f)      { *rt1 = 0.5f * (sm - rt); sgn1 = -1; *rt2 = (acmx / *rt1) * acmn - (b / *rt1) * b; }
  else if (sm > 0.0f) { *rt1 = 0.5f * (sm + rt); sgn1 = 1;  *rt2 = (acmx / *rt1) * acmn - (b / *rt1) * b; }
  else                { *rt1 = 0.5f * rt; *rt2 = -0.5f * rt; sgn1 = 1; }
  float cs; int sgn2;
  if (df >= 0.0f) { cs = df + rt; sgn2 = 1; } else { cs = df - rt; sgn2 = -1; }
  float acs = fabsf(cs);
  if (acs > ab) {
    float ct = -tb / cs;
    *sn1 = 1.0f / sqrtf(1.0f + ct * ct);
    *cs1 = ct * (*sn1);
  } else {
    if (ab == 0.0f) { *cs1 = 1.0f; *sn1 = 0.0f; }
    else {
      float tn = -cs / tb;
      *cs1 = 1.0f / sqrtf(1.0f + tn * tn);
      *sn1 = tn * (*cs1);
    }
  }
  if (sgn1 == sgn2) { float tn = *cs1; *cs1 = -(*sn1); *sn1 = tn; }
}

__device__ void eigh3_smallest(float a00, float a10, float a20,
                               float a11, float a21, float a22, float evec[3]) {
#pragma clang fp contract(off)
  float d[3], e[2], tau = 0.0f, v2 = 0.0f;
  d[0] = a00;
  {
    float xnorm = sqrtf(a20 * a20);
    if (xnorm == 0.0f) {
      tau = 0.0f; v2 = 0.0f;
      e[0] = a10; d[1] = a11; e[1] = a21; d[2] = a22;
    } else {
      float alpha = a10;
      float beta = -copysignf(slapy2f(alpha, xnorm), alpha);
      tau = (beta - alpha) / beta;
      float invs = 1.0f / (alpha - beta);
      v2 = a20 * invs;
      e[0] = beta;
      float y0 = tau * a11;
      float y1 = tau * a21;
      y0 = y0 + tau * (a21 * v2);
      y1 = y1 + (tau * v2) * a22;
      float dot = y0 + y1 * v2;
      float al = (-0.5f * tau) * dot;
      float w0 = y0 + al;
      float w1 = y1 + al * v2;
      a11 = (a11 - w0) - w0;
      a21 = (a21 - v2 * w0) - w1;
      a22 = (a22 - v2 * w1) - w1 * v2;
      d[1] = a11; e[1] = a21; d[2] = a22;
    }
  }

  float z[3][3] = {{1.0f,0.0f,0.0f},{0.0f,1.0f,0.0f},{0.0f,0.0f,1.0f}};
  const float eps = 5.9604644775390625e-08f;
  const float eps2 = 3.5527136788005009e-15f;
  const float safmin = 1.1754943508222875e-38f;
  int nmaxit = 90, jtot = 0;
  int l1 = 0;
  int l, m, lend, lsv, lendsv;
  float p, g, r, c, s, f, b_, rt1, rt2, tst;
  float wc[2], wsn[2];

outer_loop:
  if (l1 > 2) goto sorting;
  if (l1 > 0) e[l1 - 1] = 0.0f;
  {
    int mm;
    for (mm = l1; mm <= 1; ++mm) {
      tst = fabsf(e[mm]);
      if (tst == 0.0f) break;
      if (tst <= (sqrtf(fabsf(d[mm])) * sqrtf(fabsf(d[mm + 1]))) * eps) { e[mm] = 0.0f; break; }
    }
    m = (mm > 1) ? 2 : mm;
  }
  l = l1; lsv = l; lend = m; lendsv = lend; l1 = m + 1;
  if (lend == l) goto outer_loop;
  {
    float an = 0.0f;
    for (int i2 = l; i2 <= lend; ++i2) an = fmaxf(an, fabsf(d[i2]));
    for (int i2 = l; i2 < lend; ++i2) an = fmaxf(an, fabsf(e[i2]));
    if (an == 0.0f) goto outer_loop;
  }
  if (fabsf(d[lend]) < fabsf(d[l])) { lend = lsv; l = lendsv; }

  if (lend > l) {
ql40:
    if (l != lend) {
      for (m = l; m <= lend - 1; ++m) {
        tst = e[m] * e[m];
        if (tst <= (eps2 * fabsf(d[m])) * fabsf(d[m + 1]) + safmin) goto ql60;
      }
    }
    m = lend;
ql60:
    if (m < lend) e[m] = 0.0f;
    p = d[l];
    if (m == l) goto ql80;
    if (m == l + 1) {
      slaev2f(d[l], e[l], d[l + 1], &rt1, &rt2, &c, &s);
      for (int i2 = 0; i2 < 3; ++i2) {
        float temp = z[i2][l + 1];
        z[i2][l + 1] = c * temp - s * z[i2][l];
        z[i2][l]     = s * temp + c * z[i2][l];
      }
      d[l] = rt1; d[l + 1] = rt2; e[l] = 0.0f;
      l += 2;
      if (l <= lend) goto ql40;
      goto done140;
    }
    if (jtot == nmaxit) goto done140;
    jtot++;
    g = (d[l + 1] - p) / (2.0f * e[l]);
    r = slapy2f(g, 1.0f);
    g = d[m] - p + e[l] / (g + copysignf(r, g));
    s = 1.0f; c = 1.0f; p = 0.0f;
    for (int i2 = m - 1; i2 >= l; --i2) {
      f = s * e[i2]; b_ = c * e[i2];
      slartgf(g, f, &c, &s, &r);
      if (i2 != m - 1) e[i2 + 1] = r;
      g = d[i2 + 1] - p;
      r = (d[i2] - g) * s + 2.0f * c * b_;
      p = s * r;
      d[i2 + 1] = g + p;
      g = c * r - b_;
      wc[i2] = c; wsn[i2] = -s;
    }
    for (int j = m - 1; j >= l; --j) {
      float ct = wc[j], st = wsn[j];
      for (int i2 = 0; i2 < 3; ++i2) {
        float temp = z[i2][j + 1];
        z[i2][j + 1] = ct * temp - st * z[i2][j];
        z[i2][j]     = st * temp + ct * z[i2][j];
      }
    }
    d[l] -= p;
    e[l] = g;
    goto ql40;
ql80:
    d[l] = p;
    l += 1;
    if (l <= lend) goto ql40;
    goto done140;
  } else {
qr90:
    if (l != lend) {
      for (m = l; m >= lend + 1; --m) {
        tst = e[m - 1] * e[m - 1];
        if (tst <= (eps2 * fabsf(d[m])) * fabsf(d[m - 1]) + safmin) goto qr110;
      }
    }
    m = lend;
qr110:
    if (m > lend) e[m - 1] = 0.0f;
    p = d[l];
    if (m == l) goto qr130;
    if (m == l - 1) {
      slaev2f(d[l - 1], e[l - 1], d[l], &rt1, &rt2, &c, &s);
      for (int i2 = 0; i2 < 3; ++i2) {
        float temp = z[i2][l];
        z[i2][l]     = c * temp - s * z[i2][l - 1];
        z[i2][l - 1] = s * temp + c * z[i2][l - 1];
      }
      d[l - 1] = rt1; d[l] = rt2; e[l - 1] = 0.0f;
      l -= 2;
      if (l >= lend) goto qr90;
      goto done140;
    }
    if (jtot == nmaxit) goto done140;
    jtot++;
    g = (d[l - 1] - p) / (2.0f * e[l - 1]);
    r = slapy2f(g, 1.0f);
    g = d[m] - p + e[l - 1] / (g + copysignf(r, g));
    s = 1.0f; c = 1.0f; p = 0.0f;
    for (int i2 = m; i2 <= l - 1; ++i2) {
      f = s * e[i2]; b_ = c * e[i2];
      slartgf(g, f, &c, &s, &r);
      if (i2 != m) e[i2 - 1] = r;
      g = d[i2] - p;
      r = (d[i2 + 1] - g) * s + 2.0f * c * b_;
      p = s * r;
      d[i2] = g + p;
      g = c * r - b_;
      wc[i2] = c; wsn[i2] = s;
    }
    for (int j = m; j <= l - 1; ++j) {
      float ct = wc[j], st = wsn[j];
      for (int i2 = 0; i2 < 3; ++i2) {
        float temp = z[i2][j + 1];
        z[i2][j + 1] = ct * temp - st * z[i2][j];
        z[i2][j]     = st * temp + ct * z[i2][j];
      }
    }
    d[l] -= p;
    e[l - 1] = g;
    goto qr90;
qr130:
    d[l] = p;
    l -= 1;
    if (l >= lend) goto qr90;
    goto done140;
  }
done140:
  if (jtot < nmaxit) goto outer_loop;
sorting:
  for (int ii = 1; ii <= 2; ++ii) {
    int i_ = ii - 1, k = i_;
    p = d[i_];
    for (int j = ii; j <= 2; ++j) if (d[j] < p) { k = j; p = d[j]; }
    if (k != i_) {
      d[k] = d[i_]; d[i_] = p;
      for (int i2 = 0; i2 < 3; ++i2) { float tz = z[i2][i_]; z[i2][i_] = z[i2][k]; z[i2][k] = tz; }
    }
  }
  {
    float z10 = z[1][0], z20 = z[2][0];
    float sum = z10 + v2 * z20;
    evec[0] = z[0][0];
    evec[1] = z10 - tau * sum;
    evec[2] = z20 - tau * sum * v2;
  }
}

// ======================================================================
__device__ __forceinline__ float qdist(const float4 qv, const float4 cv) {
  float dot = fmaf(qv.x, cv.x, fmaf(qv.y, cv.y, qv.z * cv.z));
  return fmaf(-2.0f, dot, qv.w + cv.w);
}

__device__ __forceinline__ unsigned int distbits(float dist) {
  unsigned int du = __float_as_uint(dist);
  return (du & 0x80000000u) ? ~du : (du | 0x80000000u);
}

__device__ __forceinline__ int cell1(float v) {
  return min(GDIM - 1, max(0, (int)floorf((v - GX0) * GINVH)));
}

// ======================================================================
// Kernel A: zero cell counts/cursors + stats
// ======================================================================
__global__ __launch_bounds__(256) void zero_kernel(int* __restrict__ counts,
                                                   int* __restrict__ cursor,
                                                   float* __restrict__ stats) {
  int i = blockIdx.x * 256 + threadIdx.x;
  if (i < NCELLT) { counts[i] = 0; cursor[i] = 0; }
  if (i < 256) stats[i] = 0.0f;
}

// ======================================================================
// Kernel B: prep — pack xyz4 + cell histogram + transpose w1/w2
// ======================================================================
__global__ __launch_bounds__(256) void prep_kernel(const float* __restrict__ xyz,
                                                   const float* __restrict__ w1,
                                                   const float* __restrict__ w2,
                                                   float4* __restrict__ xyz4,
                                                   float* __restrict__ w1t,
                                                   float* __restrict__ w2t,
                                                   int* __restrict__ counts) {
  int idx = blockIdx.x * 256 + threadIdx.x;
  if (idx < BATCH * N_PTS) {
    float x = xyz[idx * 3], y = xyz[idx * 3 + 1], zz = xyz[idx * 3 + 2];
    float sq = fmaf(zz, zz, fmaf(y, y, x * x));
    xyz4[idx] = make_float4(x, y, zz, sq);
    int batch = idx >> 13;
    int cid = batch * NCELL + (cell1(x) * GDIM + cell1(y)) * GDIM + cell1(zz);
    atomicAdd(&counts[cid], 1);
  }
  if (idx < 132 * CH) {
    int cc = idx >> 7, o = idx & 127;
    w1t[idx] = (cc < 131) ? w1[o * 131 + cc] : 0.0f;
  }
  if (idx < CH * CH) {
    int cc = idx >> 7, o = idx & 127;
    w2t[idx] = w2[o * CH + cc];
  }
}

// ======================================================================
// Kernel C: exclusive scan of counts -> cellStart (single block)
// ======================================================================
__global__ __launch_bounds__(1024) void scan_kernel(const int* __restrict__ counts,
                                                    int* __restrict__ cellStart) {
  __shared__ int part[1024];
  const int tid = threadIdx.x;
  const int per = NCELLT / 1024;          // 250
  const int i0 = tid * per;
  int s = 0;
  for (int j = 0; j < per; ++j) s += counts[i0 + j];
  part[tid] = s;
  __syncthreads();
  for (int off = 1; off < 1024; off <<= 1) {
    int v = (tid >= off) ? part[tid - off] : 0;
    __syncthreads();
    part[tid] += v;
    __syncthreads();
  }
  int run = part[tid] - s;                // exclusive base
  for (int j = 0; j < per; ++j) { cellStart[i0 + j] = run; run += counts[i0 + j]; }
  if (tid == 1023) cellStart[NCELLT] = run;
}

// ======================================================================
// Kernel D: scatter points into cell-sorted order
// ======================================================================
__global__ __launch_bounds__(256) void scatter_kernel(const float4* __restrict__ xyz4,
                                                      const int* __restrict__ cellStart,
                                                      int* __restrict__ cursor,
                                                      float4* __restrict__ spts,
                                                      int* __restrict__ sidx) {
  int idx = blockIdx.x * 256 + threadIdx.x;
  if (idx < BATCH * N_PTS) {
    float4 v = xyz4[idx];
    int batch = idx >> 13;
    int cid = batch * NCELL + (cell1(v.x) * GDIM + cell1(v.y)) * GDIM + cell1(v.z);
    int pos = cellStart[cid] + atomicAdd(&cursor[cid], 1);
    spts[pos] = v;
    sidx[pos] = idx & (N_PTS - 1);
  }
}

// ======================================================================
// Kernel E: exact grid-pruned 20-NN. 256 thr = 32 queries x 8 subs.
//  Bound: per-sub exact 3-smallest over disjoint box columns (s=1..3,
//         grow while sum(min(cnt,3)) < 20; cap -> full chunked scan);
//         Tq = 20th smallest of the 24 (= 5th largest, INF pads go first)
//         -> >=20 distinct candidates <= Tq -> Tq >= true 20th (exact).
//  Exact: columns with min-dist <= Tprune (border one-sided), z-runs;
//         collect dist<=Tq -> 8-lane parallel selection (R4-proven).
// ======================================================================
__global__ __launch_bounds__(256) void knn_grid_kernel(const float4* __restrict__ spts,
                                                       const int* __restrict__ sidx,
                                                       const int* __restrict__ cellStart,
                                                       unsigned short* __restrict__ nidx) {
  __shared__ unsigned long long lst[QPB * (CAP + 2)];
  __shared__ unsigned int qcnt[QPB];
  __shared__ unsigned int qover[QPB];

  const int t = threadIdx.x;
  const int qg = t >> 3, sub = t & 7;
  const int lane = t & 63;
  const int gpos = blockIdx.x * QPB + qg;
  const int batch = gpos >> 13;
  if (sub == 0) { qcnt[qg] = 0; qover[qg] = 0; }

  const float4 qv = spts[gpos];
  const int qidx = sidx[gpos];
  const int cbase = batch * NCELL;
  const int cx = cell1(qv.x), cy = cell1(qv.y), cz = cell1(qv.z);

  // ---- bound phase: per-sub exact 3-smallest over disjoint partitions ----
  float a0 = INFINITY, a1 = INFINITY, a2 = INFINITY;
  {
    int s = 1; bool useFull = false;
    while (true) {
      a0 = INFINITY; a1 = INFINITY; a2 = INFINITY;
      int cnt = 0;
      int xlo = max(0, cx - s), xhi = min(GDIM - 1, cx + s);
      int ylo = max(0, cy - s), yhi = min(GDIM - 1, cy + s);
      int zlo = max(0, cz - s), zhi = min(GDIM - 1, cz + s);
      int m = 0;
      for (int i = xlo; i <= xhi; ++i)
        for (int j = ylo; j <= yhi; ++j) {
          if (((m++) & 7) != sub) continue;
          int rb = cbase + (i * GDIM + j) * GDIM;
          int p0 = cellStart[rb + zlo], p1 = cellStart[rb + zhi + 1];
          cnt += (p1 - p0);
          for (int p = p0; p < p1; ++p) {
            float dist = qdist(qv, spts[p]);
            float u0 = fmaxf(a0, dist); a0 = fminf(a0, dist);
            float u1 = fmaxf(a1, u0);   a1 = fminf(a1, u0);
            a2 = fminf(a2, u1);
          }
        }
      int tot = min(cnt, 3);
      tot += __shfl_xor(tot, 1, 64);
      tot += __shfl_xor(tot, 2, 64);
      tot += __shfl_xor(tot, 4, 64);
      if (tot >= 20) break;
      if (s >= 3) { useFull = true; break; }
      ++s;
    }
    if (useFull) {
      // tail queries (~1%): index-chunked full scan (chunks spatially random)
      a0 = INFINITY; a1 = INFINITY; a2 = INFINITY;
      const int pb = batch * N_PTS + sub * (N_PTS / 8);
      for (int p = pb; p < pb + N_PTS / 8; ++p) {
        float dist = qdist(qv, spts[p]);
        float u0 = fmaxf(a0, dist); a0 = fminf(a0, dist);
        float u1 = fmaxf(a1, u0);   a1 = fminf(a1, u0);
        a2 = fminf(a2, u1);
      }
    }
  }

  // ---- Tq = 20th smallest of 24 = 5th largest (5 rounds argmax-remove) ----
  float Tq = INFINITY;
  {
    int rem = 0;
    const int gb = lane & 56;
    for (int r = 0; r < 5; ++r) {
      float mymax = (rem == 0) ? a2 : (rem == 1) ? a1 : (rem == 2) ? a0 : -INFINITY;
      unsigned long long key = ((unsigned long long)distbits(mymax) << 3) | (unsigned int)sub;
      unsigned long long o;
      o = __shfl_xor(key, 1, 64); key = (o > key) ? o : key;
      o = __shfl_xor(key, 2, 64); key = (o > key) ? o : key;
      o = __shfl_xor(key, 4, 64); key = (o > key) ? o : key;
      int wl = (int)(key & 7u);
      float v = __shfl(mymax, gb | wl, 64);
      if (wl == sub) rem++;
      if (r == 4) Tq = v;
    }
  }

  // ---- exact phase ----
  const float Tprune = Tq * 1.0001f + 1e-9f;
  const float r = sqrtf(Tprune) * 1.0002f + 1e-7f;
  const int cxlo = min(GDIM - 1, max(0, (int)floorf((qv.x - r - GX0) * GINVH)));
  const int cxhi = min(GDIM - 1, max(0, (int)floorf((qv.x + r - GX0) * GINVH)));
  const int cylo = min(GDIM - 1, max(0, (int)floorf((qv.y - r - GX0) * GINVH)));
  const int cyhi = min(GDIM - 1, max(0, (int)floorf((qv.y + r - GX0) * GINVH)));
  int m2 = 0;
  for (int i = cxlo; i <= cxhi; ++i) {
    float lox = fmaf((float)i, GH, GX0), hix = lox + GH;
    float dxl = lox - qv.x; if (i == 0) dxl = -1e30f;        // border: one-sided
    float dxh = qv.x - hix; if (i == GDIM - 1) dxh = -1e30f;
    float dx = fmaxf(0.0f, fmaxf(dxl, dxh));
    float dx2 = dx * dx;
    for (int j = cylo; j <= cyhi; ++j) {
      if (((m2++) & 7) != sub) continue;
      float loy = fmaf((float)j, GH, GX0), hiy = loy + GH;
      float dyl = loy - qv.y; if (j == 0) dyl = -1e30f;
      float dyh = qv.y - hiy; if (j == GDIM - 1) dyh = -1e30f;
      float dy = fmaxf(0.0f, fmaxf(dyl, dyh));
      float d2 = fmaf(dy, dy, dx2);
      if (d2 > Tprune) continue;
      float rz = sqrtf(fmaxf(0.0f, Tprune - d2)) * 1.0002f + 1e-7f;
      int klo = min(GDIM - 1, max(0, (int)floorf((qv.z - rz - GX0) * GINVH)));
      int khi = min(GDIM - 1, max(0, (int)floorf((qv.z + rz - GX0) * GINVH)));
      int rb = cbase + (i * GDIM + j) * GDIM;
      int p0 = cellStart[rb + klo], p1 = cellStart[rb + khi + 1];
      for (int p = p0; p < p1; ++p) {
        float4 cv = spts[p];
        float dist = qdist(qv, cv);
        if (dist <= Tq) {
          unsigned long long key = ((unsigned long long)distbits(dist) << 32)
                                 | (unsigned int)sidx[p];
          unsigned int pos = atomicAdd(&qcnt[qg], 1u);
          if (pos < CAP) lst[qg * (CAP + 2) + pos] = key;
          else qover[qg] = 1u;
        }
      }
    }
  }

  // ---- selection (8 lanes per query) ----
  unsigned int n = qcnt[qg]; if (n > CAP) n = CAP;
  unsigned short* oq = nidx + ((size_t)(batch * N_PTS + qidx)) * KNN;
  if (qover[qg]) {
    if (sub == 0) {
      // exact static-register fallback (no scratch: fully unrolled)
      unsigned long long best[KNN];
#pragma unroll
      for (int j = 0; j < KNN; ++j) best[j] = ~0ULL;
      const int pb = batch * N_PTS;
      for (int m = 0; m < N_PTS; ++m) {
        float dist = qdist(qv, spts[pb + m]);
        unsigned long long pk = ((unsigned long long)distbits(dist) << 32)
                              | (unsigned int)sidx[pb + m];
        if (pk < best[KNN - 1]) {
          best[KNN - 1] = pk;
#pragma unroll
          for (int j = KNN - 1; j > 0; --j) {
            unsigned long long xx = best[j - 1], yy = best[j];
            bool sw = yy < xx;
            best[j - 1] = sw ? yy : xx;
            best[j]     = sw ? xx : yy;
          }
        }
      }
      for (int j = 0; j < KNN; ++j) oq[j] = (unsigned short)(best[j] & 0xffffu);
    }
  } else {
    for (int rr = 0; rr < KNN; ++rr) {
      unsigned long long best = ~0ULL; int bslot = 0;
      for (unsigned int s2 = sub; s2 < n; s2 += 8) {
        unsigned long long v = lst[qg * (CAP + 2) + s2];
        if (v < best) { best = v; bslot = (int)s2; }
      }
#pragma unroll
      for (int mm = 1; mm < 8; mm <<= 1) {
        unsigned long long ob = __shfl_xor(best, mm, 64);
        int obs = __shfl_xor(bslot, mm, 64);
        if (ob < best) { best = ob; bslot = obs; }
      }
      if ((bslot & 7) == sub) lst[qg * (CAP + 2) + bslot] = ~0ULL;
      if (sub == 0) oq[rr] = (unsigned short)(best & 0xffffu);
    }
  }
}

// ======================================================================
// Kernel F: covariance (sorted order) + eigh -> normals
// ======================================================================
__global__ __launch_bounds__(256) void normals_kernel(const float4* __restrict__ xyz4,
                                                      const unsigned short* __restrict__ nidx,
                                                      float4* __restrict__ nrm4) {
  int gid = blockIdx.x * 256 + threadIdx.x;
  int batch = gid >> 13, q = gid & (N_PTS - 1);
  const float4* __restrict__ xb = xyz4 + batch * N_PTS;
  const float4 qv = xb[q];
  const unsigned short* iq = nidx + (size_t)gid * KNN;
  float c00, c01, c02, c11, c12, c22;
  {
#pragma clang fp contract(off)
    c00 = 0.f; c01 = 0.f; c02 = 0.f; c11 = 0.f; c12 = 0.f; c22 = 0.f;
    for (int j = 0; j < KNN; ++j) {
      float4 pv = xb[iq[j]];
      float dx = pv.x - qv.x, dy = pv.y - qv.y, dz = pv.z - qv.z;
      c00 = c00 + dx * dx; c01 = c01 + dx * dy; c02 = c02 + dx * dz;
      c11 = c11 + dy * dy; c12 = c12 + dy * dz; c22 = c22 + dz * dz;
    }
  }
  float ev[3];
  eigh3_smallest(c00, c01, c02, c11, c12, c22, ev);
  nrm4[gid] = make_float4(ev[0], ev[1], ev[2], 0.0f);
}

// ======================================================================
// Kernel G: GEMM1 + BN stats
// ======================================================================
__global__ __launch_bounds__(256) void gemm1_stats_kernel(const float* __restrict__ x,
                                                          const float4* __restrict__ nrm4,
                                                          const float* __restrict__ w1t,
                                                          const float* __restrict__ b1,
                                                          float* __restrict__ sums,
                                                          float* __restrict__ sumsq) {
  __shared__ float lds[64 * 134];
  const int t = threadIdx.x;
  const int b = blockIdx.x >> 7;
  const int n0 = (blockIdx.x & 127) << 6;
  for (int idx = t; idx < CH * 64; idx += 256) {
    int cc = idx >> 6, nl = idx & 63;
    lds[nl * 134 + cc] = x[((size_t)(b * CH + cc)) * N_PTS + n0 + nl];
  }
  if (t < 64) {
    float4 nv = nrm4[b * N_PTS + n0 + t];
    lds[t * 134 + 128] = nv.x; lds[t * 134 + 129] = nv.y;
    lds[t * 134 + 130] = nv.z; lds[t * 134 + 131] = 0.0f;
  }
  __syncthreads();

  const int og = __builtin_amdgcn_readfirstlane(t >> 6);
  const int nl = t & 63;
  float acc[32];
#pragma unroll
  for (int k = 0; k < 32; ++k) acc[k] = b1[og * 32 + k];
  for (int c2 = 0; c2 < 66; ++c2) {
    float2 xv = *(const float2*)&lds[nl * 134 + 2 * c2];
    const float* wr0 = w1t + (2 * c2) * CH + og * 32;
    const float* wr1 = wr0 + CH;
#pragma unroll
    for (int k = 0; k < 32; ++k) acc[k] = fmaf(wr0[k], xv.x, acc[k]);
#pragma unroll
    for (int k = 0; k < 32; ++k) acc[k] = fmaf(wr1[k], xv.y, acc[k]);
  }
  __syncthreads();
#pragma unroll
  for (int k2 = 0; k2 < 16; ++k2)
    *(float2*)&lds[nl * 134 + og * 32 + 2 * k2] = make_float2(acc[2 * k2], acc[2 * k2 + 1]);
  __syncthreads();
  {
    int cc = t & 127, hf = t >> 7;
    float sm = 0.f, sq = 0.f;
    for (int rr = hf * 32; rr < hf * 32 + 32; ++rr) {
      float v = lds[rr * 134 + cc];
      sm += v; sq = fmaf(v, v, sq);
    }
    atomicAdd(&sums[cc], sm);
    atomicAdd(&sumsq[cc], sq);
  }
}

// ======================================================================
// Kernel H: finalize BN scale/shift
// ======================================================================
__global__ void bn_finalize_kernel(const float* __restrict__ sums, const float* __restrict__ sumsq,
                                   const float* __restrict__ gamma, const float* __restrict__ beta,
                                   float* __restrict__ scale, float* __restrict__ shift) {
  int c = threadIdx.x;
  if (c < CH) {
    const double cnt = (double)(BATCH * N_PTS);
    double mean = (double)sums[c] / cnt;
    double var = (double)sumsq[c] / cnt - mean * mean;
    double inv = 1.0 / sqrt(var + 1e-5);
    double sc = (double)gamma[c] * inv;
    scale[c] = (float)sc;
    shift[c] = (float)((double)beta[c] - mean * sc);
  }
}

// ======================================================================
// Kernel I: fused GEMM1 (recompute) + BN + ReLU + GEMM2 -> out
// ======================================================================
__global__ __launch_bounds__(256) void fused_out_kernel(const float* __restrict__ x,
                                                        const float4* __restrict__ nrm4,
                                                        const float* __restrict__ w1t,
                                                        const float* __restrict__ b1,
                                                        const float* __restrict__ w2t,
                                                        const float* __restrict__ b2,
                                                        const float* __restrict__ scale,
                                                        const float* __restrict__ shift,
                                                        float* __restrict__ out) {
  __shared__ float lds[64 * 134];
  const int t = threadIdx.x;
  const int b = blockIdx.x >> 7;
  const int n0 = (blockIdx.x & 127) << 6;
  for (int idx = t; idx < CH * 64; idx += 256) {
    int cc = idx >> 6, nl = idx & 63;
    lds[nl * 134 + cc] = x[((size_t)(b * CH + cc)) * N_PTS + n0 + nl];
  }
  if (t < 64) {
    float4 nv = nrm4[b * N_PTS + n0 + t];
    lds[t * 134 + 128] = nv.x; lds[t * 134 + 129] = nv.y;
    lds[t * 134 + 130] = nv.z; lds[t * 134 + 131] = 0.0f;
  }
  __syncthreads();

  const int og = __builtin_amdgcn_readfirstlane(t >> 6);
  const int nl = t & 63;
  float acc[32];
#pragma unroll
  for (int k = 0; k < 32; ++k) acc[k] = b1[og * 32 + k];
  for (int c2 = 0; c2 < 66; ++c2) {
    float2 xv = *(const float2*)&lds[nl * 134 + 2 * c2];
    const float* wr0 = w1t + (2 * c2) * CH + og * 32;
    const float* wr1 = wr0 + CH;
#pragma unroll
    for (int k = 0; k < 32; ++k) acc[k] = fmaf(wr0[k], xv.x, acc[k]);
#pragma unroll
    for (int k = 0; k < 32; ++k) acc[k] = fmaf(wr1[k], xv.y, acc[k]);
  }
#pragma unroll
  for (int k = 0; k < 32; ++k) {
    float sc = scale[og * 32 + k], sh = shift[og * 32 + k];
    acc[k] = fmaxf(fmaf(acc[k], sc, sh), 0.0f);
  }
  __syncthreads();
#pragma unroll
  for (int k2 = 0; k2 < 16; ++k2)
    *(float2*)&lds[nl * 134 + og * 32 + 2 * k2] = make_float2(acc[2 * k2], acc[2 * k2 + 1]);
  __syncthreads();

  float acc2[32];
#pragma unroll
  for (int k = 0; k < 32; ++k) acc2[k] = b2[og * 32 + k];
  for (int c2 = 0; c2 < 64; ++c2) {
    float2 hv = *(const float2*)&lds[nl * 134 + 2 * c2];
    const float* wr0 = w2t + (2 * c2) * CH + og * 32;
    const float* wr1 = wr0 + CH;
#pragma unroll
    for (int k = 0; k < 32; ++k) acc2[k] = fmaf(wr0[k], hv.x, acc2[k]);
#pragma unroll
    for (int k = 0; k < 32; ++k) acc2[k] = fmaf(wr1[k], hv.y, acc2[k]);
  }
#pragma unroll
  for (int k = 0; k < 32; ++k) {
    int o = og * 32 + k;
    out[((size_t)(b * CH + o)) * N_PTS + n0 + nl] = acc2[k];
  }
}

// ======================================================================
extern "C" void kernel_launch(void* const* d_in, const int* in_sizes, int n_in,
                              void* d_out, int out_size, void* d_ws, size_t ws_size,
                              hipStream_t stream) {
  const float* x     = (const float*)d_in[0];
  const float* xyz   = (const float*)d_in[1];
  const float* w1    = (const float*)d_in[2];
  const float* b1    = (const float*)d_in[3];
  const float* gamma = (const float*)d_in[4];
  const float* beta  = (const float*)d_in[5];
  const float* w2    = (const float*)d_in[6];
  const float* b2    = (const float*)d_in[7];
  float* out = (float*)d_out;

  float* W = (float*)d_ws;
  float4* xyz4 = (float4*)W;                               // 131072 f
  float4* nrm4 = (float4*)(W + 131072);                    // 131072 f
  float* w1t   = W + 262144;                               // 16896
  float* w2t   = W + 279040;                               // 16384
  float* stats = W + 295424;                               // 256
  float* scale = W + 295680;                               // 128
  float* shift = W + 295808;                               // 128
  unsigned short* nidx = (unsigned short*)(W + 295936);    // 327680 f worth
  int* counts    = (int*)(W + 623616);                     // 256000
  int* cellStart = (int*)(W + 879616);                     // 256001
  int* cursor    = (int*)(W + 1135620);                    // 256000
  float4* spts   = (float4*)(W + 1391620);                 // 131072 f (16B aligned)
  int* sidx      = (int*)(W + 1522692);                    // 32768

  zero_kernel<<<(NCELLT + 255) / 256, 256, 0, stream>>>(counts, cursor, stats);
  prep_kernel<<<128, 256, 0, stream>>>(xyz, w1, w2, xyz4, w1t, w2t, counts);
  scan_kernel<<<1, 1024, 0, stream>>>(counts, cellStart);
  scatter_kernel<<<128, 256, 0, stream>>>(xyz4, cellStart, cursor, spts, sidx);
  knn_grid_kernel<<<BATCH * N_PTS / QPB, 256, 0, stream>>>(spts, sidx, cellStart, nidx);
  normals_kernel<<<BATCH * N_PTS / 256, 256, 0, stream>>>(xyz4, nidx, nrm4);
  gemm1_stats_kernel<<<BATCH * N_PTS / 64, 256, 0, stream>>>(x, nrm4, w1t, b1, stats, stats + 128);
  bn_finalize_kernel<<<1, 128, 0, stream>>>(stats, stats + 128, gamma, beta, scale, shift);
  fused_out_kernel<<<BATCH * N_PTS / 64, 256, 0, stream>>>(x, nrm4, w1t, b1, w2t, b2, scale, shift, out);
}

// Round 7
// 2064.870 us; speedup vs baseline: 3.3726x; 3.3726x over previous
//
#include <hip/hip_runtime.h>
#include <math.h>

#define N_PTS 8192
#define BATCH 4
#define CH 128
#define KNN 20
#define CAP 112
#define QPB 32            // queries per knn block
#define GDIM 40
#define GX0 -5.2f
#define GH 0.26f
#define GINVH (1.0f/0.26f)
#define NCELL (GDIM*GDIM*GDIM)            // 64000 per batch
#define NCELLT (NCELL*BATCH)              // 256000 total

// ======================================================================
// LAPACK ssyevd emulation for 3x3 symmetric (lower), SINGLE precision.
// (verified passing rounds 2-6 — do not perturb numerics)
// ======================================================================

__device__ __forceinline__ float slapy2f(float x, float y) {
#pragma clang fp contract(off)
  float ax = fabsf(x), ay = fabsf(y);
  float w = fmaxf(ax, ay), z = fminf(ax, ay);
  if (z == 0.0f) return w;
  float t = z / w;
  return w * sqrtf(1.0f + t * t);
}

__device__ __forceinline__ void slartgf(float f, float g, float* cs, float* sn, float* r) {
#pragma clang fp contract(off)
  if (g == 0.0f) { *cs = 1.0f; *sn = 0.0f; *r = f; }
  else if (f == 0.0f) { *cs = 0.0f; *sn = copysignf(1.0f, g); *r = fabsf(g); }
  else {
    float f1 = fabsf(f);
    float d = sqrtf(f * f + g * g);
    *cs = f1 / d;
    *r = copysignf(d, f);
    *sn = g / (*r);
  }
}

__device__ void slaev2f(float a, float b, float c, float* rt1, float* rt2,
                        float* cs1, float* sn1) {
#pragma clang fp contract(off)
  float sm = a + c, df = a - c, adf = fabsf(df);
  float tb = b + b, ab = fabsf(tb);
  float acmx, acmn;
  if (fabsf(a) > fabsf(c)) { acmx = a; acmn = c; } else { acmx = c; acmn = a; }
  float rt;
  if (adf > ab)      { float q = ab / adf;  rt = adf * sqrtf(1.0f + q * q); }
  else if (adf < ab) { float q = adf / ab;  rt = ab * sqrtf(1.0f + q * q); }
  else               rt = ab * sqrtf(2.0f);
  int sgn1;
  if (sm < 0.0f)      { *rt1 = 0.5f * (sm - rt); sgn1 = -1; *rt2 = (acmx / *rt1) * acmn - (b / *rt1) * b; }
  else if (sm > 0.0f) { *rt1 = 0.5f * (sm + rt); sgn1 = 1;  *rt2 = (acmx / *rt1) * acmn - (b / *rt1) * b; }
  else                { *rt1 = 0.5f * rt; *rt2 = -0.5f * rt; sgn1 = 1; }
  float cs; int sgn2;
  if (df >= 0.0f) { cs = df + rt; sgn2 = 1; } else { cs = df - rt; sgn2 = -1; }
  float acs = fabsf(cs);
  if (acs > ab) {
    float ct = -tb / cs;
    *sn1 = 1.0f / sqrtf(1.0f + ct * ct);
    *cs1 = ct * (*sn1);
  } else {
    if (ab == 0.0f) { *cs1 = 1.0f; *sn1 = 0.0f; }
    else {
      float tn = -cs / tb;
      *cs1 = 1.0f / sqrtf(1.0f + tn * tn);
      *sn1 = tn * (*cs1);
    }
  }
  if (sgn1 == sgn2) { float tn = *cs1; *cs1 = -(*sn1); *sn1 = tn; }
}

__device__ void eigh3_smallest(float a00, float a10, float a20,
                               float a11, float a21, float a22, float evec[3]) {
#pragma clang fp contract(off)
  float d[3], e[2], tau = 0.0f, v2 = 0.0f;
  d[0] = a00;
  {
    float xnorm = sqrtf(a20 * a20);
    if (xnorm == 0.0f) {
      tau = 0.0f; v2 = 0.0f;
      e[0] = a10; d[1] = a11; e[1] = a21; d[2] = a22;
    } else {
      float alpha = a10;
      float beta = -copysignf(slapy2f(alpha, xnorm), alpha);
      tau = (beta - alpha) / beta;
      float invs = 1.0f / (alpha - beta);
      v2 = a20 * invs;
      e[0] = beta;
      float y0 = tau * a11;
      float y1 = tau * a21;
      y0 = y0 + tau * (a21 * v2);
      y1 = y1 + (tau * v2) * a22;
      float dot = y0 + y1 * v2;
      float al = (-0.5f * tau) * dot;
      float w0 = y0 + al;
      float w1 = y1 + al * v2;
      a11 = (a11 - w0) - w0;
      a21 = (a21 - v2 * w0) - w1;
      a22 = (a22 - v2 * w1) - w1 * v2;
      d[1] = a11; e[1] = a21; d[2] = a22;
    }
  }

  float z[3][3] = {{1.0f,0.0f,0.0f},{0.0f,1.0f,0.0f},{0.0f,0.0f,1.0f}};
  const float eps = 5.9604644775390625e-08f;
  const float eps2 = 3.5527136788005009e-15f;
  const float safmin = 1.1754943508222875e-38f;
  int nmaxit = 90, jtot = 0;
  int l1 = 0;
  int l, m, lend, lsv, lendsv;
  float p, g, r, c, s, f, b_, rt1, rt2, tst;
  float wc[2], wsn[2];

outer_loop:
  if (l1 > 2) goto sorting;
  if (l1 > 0) e[l1 - 1] = 0.0f;
  {
    int mm;
    for (mm = l1; mm <= 1; ++mm) {
      tst = fabsf(e[mm]);
      if (tst == 0.0f) break;
      if (tst <= (sqrtf(fabsf(d[mm])) * sqrtf(fabsf(d[mm + 1]))) * eps) { e[mm] = 0.0f; break; }
    }
    m = (mm > 1) ? 2 : mm;
  }
  l = l1; lsv = l; lend = m; lendsv = lend; l1 = m + 1;
  if (lend == l) goto outer_loop;
  {
    float an = 0.0f;
    for (int i2 = l; i2 <= lend; ++i2) an = fmaxf(an, fabsf(d[i2]));
    for (int i2 = l; i2 < lend; ++i2) an = fmaxf(an, fabsf(e[i2]));
    if (an == 0.0f) goto outer_loop;
  }
  if (fabsf(d[lend]) < fabsf(d[l])) { lend = lsv; l = lendsv; }

  if (lend > l) {
ql40:
    if (l != lend) {
      for (m = l; m <= lend - 1; ++m) {
        tst = e[m] * e[m];
        if (tst <= (eps2 * fabsf(d[m])) * fabsf(d[m + 1]) + safmin) goto ql60;
      }
    }
    m = lend;
ql60:
    if (m < lend) e[m] = 0.0f;
    p = d[l];
    if (m == l) goto ql80;
    if (m == l + 1) {
      slaev2f(d[l], e[l], d[l + 1], &rt1, &rt2, &c, &s);
      for (int i2 = 0; i2 < 3; ++i2) {
        float temp = z[i2][l + 1];
        z[i2][l + 1] = c * temp - s * z[i2][l];
        z[i2][l]     = s * temp + c * z[i2][l];
      }
      d[l] = rt1; d[l + 1] = rt2; e[l] = 0.0f;
      l += 2;
      if (l <= lend) goto ql40;
      goto done140;
    }
    if (jtot == nmaxit) goto done140;
    jtot++;
    g = (d[l + 1] - p) / (2.0f * e[l]);
    r = slapy2f(g, 1.0f);
    g = d[m] - p + e[l] / (g + copysignf(r, g));
    s = 1.0f; c = 1.0f; p = 0.0f;
    for (int i2 = m - 1; i2 >= l; --i2) {
      f = s * e[i2]; b_ = c * e[i2];
      slartgf(g, f, &c, &s, &r);
      if (i2 != m - 1) e[i2 + 1] = r;
      g = d[i2 + 1] - p;
      r = (d[i2] - g) * s + 2.0f * c * b_;
      p = s * r;
      d[i2 + 1] = g + p;
      g = c * r - b_;
      wc[i2] = c; wsn[i2] = -s;
    }
    for (int j = m - 1; j >= l; --j) {
      float ct = wc[j], st = wsn[j];
      for (int i2 = 0; i2 < 3; ++i2) {
        float temp = z[i2][j + 1];
        z[i2][j + 1] = ct * temp - st * z[i2][j];
        z[i2][j]     = st * temp + ct * z[i2][j];
      }
    }
    d[l] -= p;
    e[l] = g;
    goto ql40;
ql80:
    d[l] = p;
    l += 1;
    if (l <= lend) goto ql40;
    goto done140;
  } else {
qr90:
    if (l != lend) {
      for (m = l; m >= lend + 1; --m) {
        tst = e[m - 1] * e[m - 1];
        if (tst <= (eps2 * fabsf(d[m])) * fabsf(d[m - 1]) + safmin) goto qr110;
      }
    }
    m = lend;
qr110:
    if (m > lend) e[m - 1] = 0.0f;
    p = d[l];
    if (m == l) goto qr130;
    if (m == l - 1) {
      slaev2f(d[l - 1], e[l - 1], d[l], &rt1, &rt2, &c, &s);
      for (int i2 = 0; i2 < 3; ++i2) {
        float temp = z[i2][l];
        z[i2][l]     = c * temp - s * z[i2][l - 1];
        z[i2][l - 1] = s * temp + c * z[i2][l - 1];
      }
      d[l - 1] = rt1; d[l] = rt2; e[l - 1] = 0.0f;
      l -= 2;
      if (l >= lend) goto qr90;
      goto done140;
    }
    if (jtot == nmaxit) goto done140;
    jtot++;
    g = (d[l - 1] - p) / (2.0f * e[l - 1]);
    r = slapy2f(g, 1.0f);
    g = d[m] - p + e[l - 1] / (g + copysignf(r, g));
    s = 1.0f; c = 1.0f; p = 0.0f;
    for (int i2 = m; i2 <= l - 1; ++i2) {
      f = s * e[i2]; b_ = c * e[i2];
      slartgf(g, f, &c, &s, &r);
      if (i2 != m) e[i2 - 1] = r;
      g = d[i2] - p;
      r = (d[i2 + 1] - g) * s + 2.0f * c * b_;
      p = s * r;
      d[i2] = g + p;
      g = c * r - b_;
      wc[i2] = c; wsn[i2] = s;
    }
    for (int j = m; j <= l - 1; ++j) {
      float ct = wc[j], st = wsn[j];
      for (int i2 = 0; i2 < 3; ++i2) {
        float temp = z[i2][j + 1];
        z[i2][j + 1] = ct * temp - st * z[i2][j];
        z[i2][j]     = st * temp + ct * z[i2][j];
      }
    }
    d[l] -= p;
    e[l - 1] = g;
    goto qr90;
qr130:
    d[l] = p;
    l -= 1;
    if (l >= lend) goto qr90;
    goto done140;
  }
done140:
  if (jtot < nmaxit) goto outer_loop;
sorting:
  for (int ii = 1; ii <= 2; ++ii) {
    int i_ = ii - 1, k = i_;
    p = d[i_];
    for (int j = ii; j <= 2; ++j) if (d[j] < p) { k = j; p = d[j]; }
    if (k != i_) {
      d[k] = d[i_]; d[i_] = p;
      for (int i2 = 0; i2 < 3; ++i2) { float tz = z[i2][i_]; z[i2][i_] = z[i2][k]; z[i2][k] = tz; }
    }
  }
  {
    float z10 = z[1][0], z20 = z[2][0];
    float sum = z10 + v2 * z20;
    evec[0] = z[0][0];
    evec[1] = z10 - tau * sum;
    evec[2] = z20 - tau * sum * v2;
  }
}

// ======================================================================
__device__ __forceinline__ float qdist(const float4 qv, const float4 cv) {
  float dot = fmaf(qv.x, cv.x, fmaf(qv.y, cv.y, qv.z * cv.z));
  return fmaf(-2.0f, dot, qv.w + cv.w);
}

__device__ __forceinline__ unsigned int distbits(float dist) {
  unsigned int du = __float_as_uint(dist);
  return (du & 0x80000000u) ? ~du : (du | 0x80000000u);
}

__device__ __forceinline__ int cell1(float v) {
  return min(GDIM - 1, max(0, (int)floorf((v - GX0) * GINVH)));
}

// ======================================================================
// Kernel A: zero cell counts/cursors + stats
// ======================================================================
__global__ __launch_bounds__(256) void zero_kernel(int* __restrict__ counts,
                                                   int* __restrict__ cursor,
                                                   float* __restrict__ stats) {
  int i = blockIdx.x * 256 + threadIdx.x;
  if (i < NCELLT) { counts[i] = 0; cursor[i] = 0; }
  if (i < 256) stats[i] = 0.0f;
}

// ======================================================================
// Kernel B: prep — pack xyz4 + cell histogram + transpose w1/w2
// ======================================================================
__global__ __launch_bounds__(256) void prep_kernel(const float* __restrict__ xyz,
                                                   const float* __restrict__ w1,
                                                   const float* __restrict__ w2,
                                                   float4* __restrict__ xyz4,
                                                   float* __restrict__ w1t,
                                                   float* __restrict__ w2t,
                                                   int* __restrict__ counts) {
  int idx = blockIdx.x * 256 + threadIdx.x;
  if (idx < BATCH * N_PTS) {
    float x = xyz[idx * 3], y = xyz[idx * 3 + 1], zz = xyz[idx * 3 + 2];
    float sq = fmaf(zz, zz, fmaf(y, y, x * x));
    xyz4[idx] = make_float4(x, y, zz, sq);
    int batch = idx >> 13;
    int cid = batch * NCELL + (cell1(x) * GDIM + cell1(y)) * GDIM + cell1(zz);
    atomicAdd(&counts[cid], 1);
  }
  if (idx < 132 * CH) {
    int cc = idx >> 7, o = idx & 127;
    w1t[idx] = (cc < 131) ? w1[o * 131 + cc] : 0.0f;
  }
  if (idx < CH * CH) {
    int cc = idx >> 7, o = idx & 127;
    w2t[idx] = w2[o * CH + cc];
  }
}

// ======================================================================
// Kernel C: exclusive scan of counts -> cellStart (single block)
// ======================================================================
__global__ __launch_bounds__(1024) void scan_kernel(const int* __restrict__ counts,
                                                    int* __restrict__ cellStart) {
  __shared__ int part[1024];
  const int tid = threadIdx.x;
  const int per = NCELLT / 1024;          // 250
  const int i0 = tid * per;
  int s = 0;
  for (int j = 0; j < per; ++j) s += counts[i0 + j];
  part[tid] = s;
  __syncthreads();
  for (int off = 1; off < 1024; off <<= 1) {
    int v = (tid >= off) ? part[tid - off] : 0;
    __syncthreads();
    part[tid] += v;
    __syncthreads();
  }
  int run = part[tid] - s;                // exclusive base
  for (int j = 0; j < per; ++j) { cellStart[i0 + j] = run; run += counts[i0 + j]; }
  if (tid == 1023) cellStart[NCELLT] = run;
}

// ======================================================================
// Kernel D: scatter points into cell-sorted order
// ======================================================================
__global__ __launch_bounds__(256) void scatter_kernel(const float4* __restrict__ xyz4,
                                                      const int* __restrict__ cellStart,
                                                      int* __restrict__ cursor,
                                                      float4* __restrict__ spts,
                                                      int* __restrict__ sidx) {
  int idx = blockIdx.x * 256 + threadIdx.x;
  if (idx < BATCH * N_PTS) {
    float4 v = xyz4[idx];
    int batch = idx >> 13;
    int cid = batch * NCELL + (cell1(v.x) * GDIM + cell1(v.y)) * GDIM + cell1(v.z);
    int pos = cellStart[cid] + atomicAdd(&cursor[cid], 1);
    spts[pos] = v;
    sidx[pos] = idx & (N_PTS - 1);
  }
}

// ======================================================================
// Kernel E: exact grid-pruned 20-NN. 256 thr = 32 queries x 8 subs.
//  Bound: z-stratified point partition (p ≡ sub mod 8, stride-8 walk of
//         each column z-run) — UNBIASED 1/8 samples per sub (R6's column
//         partition was spatially biased -> loose Tq -> mass fallback).
//         Per-sub exact 3-smallest; grow s=1..6 while Σ min(seen,3) < 20;
//         cap -> index-chunked full scan (R4-tight). Tq = 20th smallest
//         of 24 (5 rounds argmax-remove; >=20 distinct cands <= Tq =>
//         Tq >= true 20th, exact).
//  Exact: columns with min-dist <= Tprune (border one-sided), z-runs;
//         collect dist<=Tq -> 8-lane parallel selection (R4-proven).
// ======================================================================
__global__ __launch_bounds__(256) void knn_grid_kernel(const float4* __restrict__ spts,
                                                       const int* __restrict__ sidx,
                                                       const int* __restrict__ cellStart,
                                                       unsigned short* __restrict__ nidx) {
  __shared__ unsigned long long lst[QPB * (CAP + 2)];
  __shared__ unsigned int qcnt[QPB];
  __shared__ unsigned int qover[QPB];

  const int t = threadIdx.x;
  const int qg = t >> 3, sub = t & 7;
  const int lane = t & 63;
  const int gpos = blockIdx.x * QPB + qg;
  const int batch = gpos >> 13;
  if (sub == 0) { qcnt[qg] = 0; qover[qg] = 0; }

  const float4 qv = spts[gpos];
  const int qidx = sidx[gpos];
  const int cbase = batch * NCELL;
  const int cx = cell1(qv.x), cy = cell1(qv.y), cz = cell1(qv.z);

  // ---- bound phase: per-sub exact 3-smallest over z-stratified samples ----
  float a0 = INFINITY, a1 = INFINITY, a2 = INFINITY;
  {
    bool ok = false;
    for (int s = 1; s <= 6 && !ok; ++s) {
      a0 = INFINITY; a1 = INFINITY; a2 = INFINITY;
      int seen = 0;
      int xlo = max(0, cx - s), xhi = min(GDIM - 1, cx + s);
      int ylo = max(0, cy - s), yhi = min(GDIM - 1, cy + s);
      int zlo = max(0, cz - s), zhi = min(GDIM - 1, cz + s);
      for (int i = xlo; i <= xhi; ++i)
        for (int j = ylo; j <= yhi; ++j) {
          int rb = cbase + (i * GDIM + j) * GDIM;
          int p0 = cellStart[rb + zlo], p1 = cellStart[rb + zhi + 1];
          for (int p = p0 + ((sub - p0) & 7); p < p1; p += 8) {
            float dist = qdist(qv, spts[p]);
            ++seen;
            float u0 = fmaxf(a0, dist); a0 = fminf(a0, dist);
            float u1 = fmaxf(a1, u0);   a1 = fminf(a1, u0);
            a2 = fminf(a2, u1);
          }
        }
      int tot = min(seen, 3);
      tot += __shfl_xor(tot, 1, 64);
      tot += __shfl_xor(tot, 2, 64);
      tot += __shfl_xor(tot, 4, 64);
      ok = (tot >= 20);
    }
    if (!ok) {
      // deep-tail queries: index-chunked full scan (spatially random => tight)
      a0 = INFINITY; a1 = INFINITY; a2 = INFINITY;
      const int pb = batch * N_PTS + sub * (N_PTS / 8);
      for (int p = pb; p < pb + N_PTS / 8; ++p) {
        float dist = qdist(qv, spts[p]);
        float u0 = fmaxf(a0, dist); a0 = fminf(a0, dist);
        float u1 = fmaxf(a1, u0);   a1 = fminf(a1, u0);
        a2 = fminf(a2, u1);
      }
    }
  }

  // ---- Tq = 20th smallest of 24 = 5th largest (5 rounds argmax-remove) ----
  float Tq = INFINITY;
  {
    int rem = 0;
    const int gb = lane & 56;
    for (int r = 0; r < 5; ++r) {
      float mymax = (rem == 0) ? a2 : (rem == 1) ? a1 : (rem == 2) ? a0 : -INFINITY;
      unsigned long long key = ((unsigned long long)distbits(mymax) << 3) | (unsigned int)sub;
      unsigned long long o;
      o = __shfl_xor(key, 1, 64); key = (o > key) ? o : key;
      o = __shfl_xor(key, 2, 64); key = (o > key) ? o : key;
      o = __shfl_xor(key, 4, 64); key = (o > key) ? o : key;
      int wl = (int)(key & 7u);
      float v = __shfl(mymax, gb | wl, 64);
      if (wl == sub) rem++;
      if (r == 4) Tq = v;
    }
  }

  // ---- exact phase ----
  const float Tprune = Tq * 1.0001f + 1e-9f;
  const float r = sqrtf(Tprune) * 1.0002f + 1e-7f;
  const int cxlo = min(GDIM - 1, max(0, (int)floorf((qv.x - r - GX0) * GINVH)));
  const int cxhi = min(GDIM - 1, max(0, (int)floorf((qv.x + r - GX0) * GINVH)));
  const int cylo = min(GDIM - 1, max(0, (int)floorf((qv.y - r - GX0) * GINVH)));
  const int cyhi = min(GDIM - 1, max(0, (int)floorf((qv.y + r - GX0) * GINVH)));
  int m2 = 0;
  for (int i = cxlo; i <= cxhi; ++i) {
    float lox = fmaf((float)i, GH, GX0), hix = lox + GH;
    float dxl = lox - qv.x; if (i == 0) dxl = -1e30f;        // border: one-sided
    float dxh = qv.x - hix; if (i == GDIM - 1) dxh = -1e30f;
    float dx = fmaxf(0.0f, fmaxf(dxl, dxh));
    float dx2 = dx * dx;
    for (int j = cylo; j <= cyhi; ++j) {
      if (((m2++) & 7) != sub) continue;
      float loy = fmaf((float)j, GH, GX0), hiy = loy + GH;
      float dyl = loy - qv.y; if (j == 0) dyl = -1e30f;
      float dyh = qv.y - hiy; if (j == GDIM - 1) dyh = -1e30f;
      float dy = fmaxf(0.0f, fmaxf(dyl, dyh));
      float d2 = fmaf(dy, dy, dx2);
      if (d2 > Tprune) continue;
      float rz = sqrtf(fmaxf(0.0f, Tprune - d2)) * 1.0002f + 1e-7f;
      int klo = min(GDIM - 1, max(0, (int)floorf((qv.z - rz - GX0) * GINVH)));
      int khi = min(GDIM - 1, max(0, (int)floorf((qv.z + rz - GX0) * GINVH)));
      int rb = cbase + (i * GDIM + j) * GDIM;
      int p0 = cellStart[rb + klo], p1 = cellStart[rb + khi + 1];
      for (int p = p0; p < p1; ++p) {
        float4 cv = spts[p];
        float dist = qdist(qv, cv);
        if (dist <= Tq) {
          unsigned long long key = ((unsigned long long)distbits(dist) << 32)
                                 | (unsigned int)sidx[p];
          unsigned int pos = atomicAdd(&qcnt[qg], 1u);
          if (pos < CAP) lst[qg * (CAP + 2) + pos] = key;
          else qover[qg] = 1u;
        }
      }
    }
  }

  // ---- selection (8 lanes per query) ----
  unsigned int n = qcnt[qg]; if (n > CAP) n = CAP;
  unsigned short* oq = nidx + ((size_t)(batch * N_PTS + qidx)) * KNN;
  if (qover[qg]) {
    if (sub == 0) {
      // exact static-register fallback (fully unrolled, no scratch)
      unsigned long long best[KNN];
#pragma unroll
      for (int j = 0; j < KNN; ++j) best[j] = ~0ULL;
      const int pb = batch * N_PTS;
      for (int m = 0; m < N_PTS; ++m) {
        float dist = qdist(qv, spts[pb + m]);
        unsigned long long pk = ((unsigned long long)distbits(dist) << 32)
                              | (unsigned int)sidx[pb + m];
        if (pk < best[KNN - 1]) {
          best[KNN - 1] = pk;
#pragma unroll
          for (int j = KNN - 1; j > 0; --j) {
            unsigned long long xx = best[j - 1], yy = best[j];
            bool sw = yy < xx;
            best[j - 1] = sw ? yy : xx;
            best[j]     = sw ? xx : yy;
          }
        }
      }
      for (int j = 0; j < KNN; ++j) oq[j] = (unsigned short)(best[j] & 0xffffu);
    }
  } else {
    for (int rr = 0; rr < KNN; ++rr) {
      unsigned long long best = ~0ULL; int bslot = 0;
      for (unsigned int s2 = sub; s2 < n; s2 += 8) {
        unsigned long long v = lst[qg * (CAP + 2) + s2];
        if (v < best) { best = v; bslot = (int)s2; }
      }
#pragma unroll
      for (int mm = 1; mm < 8; mm <<= 1) {
        unsigned long long ob = __shfl_xor(best, mm, 64);
        int obs = __shfl_xor(bslot, mm, 64);
        if (ob < best) { best = ob; bslot = obs; }
      }
      if ((bslot & 7) == sub) lst[qg * (CAP + 2) + bslot] = ~0ULL;
      if (sub == 0) oq[rr] = (unsigned short)(best & 0xffffu);
    }
  }
}

// ======================================================================
// Kernel F: covariance (sorted order) + eigh -> normals
// ======================================================================
__global__ __launch_bounds__(256) void normals_kernel(const float4* __restrict__ xyz4,
                                                      const unsigned short* __restrict__ nidx,
                                                      float4* __restrict__ nrm4) {
  int gid = blockIdx.x * 256 + threadIdx.x;
  int batch = gid >> 13, q = gid & (N_PTS - 1);
  const float4* __restrict__ xb = xyz4 + batch * N_PTS;
  const float4 qv = xb[q];
  const unsigned short* iq = nidx + (size_t)gid * KNN;
  float c00, c01, c02, c11, c12, c22;
  {
#pragma clang fp contract(off)
    c00 = 0.f; c01 = 0.f; c02 = 0.f; c11 = 0.f; c12 = 0.f; c22 = 0.f;
    for (int j = 0; j < KNN; ++j) {
      float4 pv = xb[iq[j]];
      float dx = pv.x - qv.x, dy = pv.y - qv.y, dz = pv.z - qv.z;
      c00 = c00 + dx * dx; c01 = c01 + dx * dy; c02 = c02 + dx * dz;
      c11 = c11 + dy * dy; c12 = c12 + dy * dz; c22 = c22 + dz * dz;
    }
  }
  float ev[3];
  eigh3_smallest(c00, c01, c02, c11, c12, c22, ev);
  nrm4[gid] = make_float4(ev[0], ev[1], ev[2], 0.0f);
}

// ======================================================================
// Kernel G: GEMM1 + BN stats
// ======================================================================
__global__ __launch_bounds__(256) void gemm1_stats_kernel(const float* __restrict__ x,
                                                          const float4* __restrict__ nrm4,
                                                          const float* __restrict__ w1t,
                                                          const float* __restrict__ b1,
                                                          float* __restrict__ sums,
                                                          float* __restrict__ sumsq) {
  __shared__ float lds[64 * 134];
  const int t = threadIdx.x;
  const int b = blockIdx.x >> 7;
  const int n0 = (blockIdx.x & 127) << 6;
  for (int idx = t; idx < CH * 64; idx += 256) {
    int cc = idx >> 6, nl = idx & 63;
    lds[nl * 134 + cc] = x[((size_t)(b * CH + cc)) * N_PTS + n0 + nl];
  }
  if (t < 64) {
    float4 nv = nrm4[b * N_PTS + n0 + t];
    lds[t * 134 + 128] = nv.x; lds[t * 134 + 129] = nv.y;
    lds[t * 134 + 130] = nv.z; lds[t * 134 + 131] = 0.0f;
  }
  __syncthreads();

  const int og = __builtin_amdgcn_readfirstlane(t >> 6);
  const int nl = t & 63;
  float acc[32];
#pragma unroll
  for (int k = 0; k < 32; ++k) acc[k] = b1[og * 32 + k];
  for (int c2 = 0; c2 < 66; ++c2) {
    float2 xv = *(const float2*)&lds[nl * 134 + 2 * c2];
    const float* wr0 = w1t + (2 * c2) * CH + og * 32;
    const float* wr1 = wr0 + CH;
#pragma unroll
    for (int k = 0; k < 32; ++k) acc[k] = fmaf(wr0[k], xv.x, acc[k]);
#pragma unroll
    for (int k = 0; k < 32; ++k) acc[k] = fmaf(wr1[k], xv.y, acc[k]);
  }
  __syncthreads();
#pragma unroll
  for (int k2 = 0; k2 < 16; ++k2)
    *(float2*)&lds[nl * 134 + og * 32 + 2 * k2] = make_float2(acc[2 * k2], acc[2 * k2 + 1]);
  __syncthreads();
  {
    int cc = t & 127, hf = t >> 7;
    float sm = 0.f, sq = 0.f;
    for (int rr = hf * 32; rr < hf * 32 + 32; ++rr) {
      float v = lds[rr * 134 + cc];
      sm += v; sq = fmaf(v, v, sq);
    }
    atomicAdd(&sums[cc], sm);
    atomicAdd(&sumsq[cc], sq);
  }
}

// ======================================================================
// Kernel H: finalize BN scale/shift
// ======================================================================
__global__ void bn_finalize_kernel(const float* __restrict__ sums, const float* __restrict__ sumsq,
                                   const float* __restrict__ gamma, const float* __restrict__ beta,
                                   float* __restrict__ scale, float* __restrict__ shift) {
  int c = threadIdx.x;
  if (c < CH) {
    const double cnt = (double)(BATCH * N_PTS);
    double mean = (double)sums[c] / cnt;
    double var = (double)sumsq[c] / cnt - mean * mean;
    double inv = 1.0 / sqrt(var + 1e-5);
    double sc = (double)gamma[c] * inv;
    scale[c] = (float)sc;
    shift[c] = (float)((double)beta[c] - mean * sc);
  }
}

// ======================================================================
// Kernel I: fused GEMM1 (recompute) + BN + ReLU + GEMM2 -> out
// ======================================================================
__global__ __launch_bounds__(256) void fused_out_kernel(const float* __restrict__ x,
                                                        const float4* __restrict__ nrm4,
                                                        const float* __restrict__ w1t,
                                                        const float* __restrict__ b1,
                                                        const float* __restrict__ w2t,
                                                        const float* __restrict__ b2,
                                                        const float* __restrict__ scale,
                                                        const float* __restrict__ shift,
                                                        float* __restrict__ out) {
  __shared__ float lds[64 * 134];
  const int t = threadIdx.x;
  const int b = blockIdx.x >> 7;
  const int n0 = (blockIdx.x & 127) << 6;
  for (int idx = t; idx < CH * 64; idx += 256) {
    int cc = idx >> 6, nl = idx & 63;
    lds[nl * 134 + cc] = x[((size_t)(b * CH + cc)) * N_PTS + n0 + nl];
  }
  if (t < 64) {
    float4 nv = nrm4[b * N_PTS + n0 + t];
    lds[t * 134 + 128] = nv.x; lds[t * 134 + 129] = nv.y;
    lds[t * 134 + 130] = nv.z; lds[t * 134 + 131] = 0.0f;
  }
  __syncthreads();

  const int og = __builtin_amdgcn_readfirstlane(t >> 6);
  const int nl = t & 63;
  float acc[32];
#pragma unroll
  for (int k = 0; k < 32; ++k) acc[k] = b1[og * 32 + k];
  for (int c2 = 0; c2 < 66; ++c2) {
    float2 xv = *(const float2*)&lds[nl * 134 + 2 * c2];
    const float* wr0 = w1t + (2 * c2) * CH + og * 32;
    const float* wr1 = wr0 + CH;
#pragma unroll
    for (int k = 0; k < 32; ++k) acc[k] = fmaf(wr0[k], xv.x, acc[k]);
#pragma unroll
    for (int k = 0; k < 32; ++k) acc[k] = fmaf(wr1[k], xv.y, acc[k]);
  }
#pragma unroll
  for (int k = 0; k < 32; ++k) {
    float sc = scale[og * 32 + k], sh = shift[og * 32 + k];
    acc[k] = fmaxf(fmaf(acc[k], sc, sh), 0.0f);
  }
  __syncthreads();
#pragma unroll
  for (int k2 = 0; k2 < 16; ++k2)
    *(float2*)&lds[nl * 134 + og * 32 + 2 * k2] = make_float2(acc[2 * k2], acc[2 * k2 + 1]);
  __syncthreads();

  float acc2[32];
#pragma unroll
  for (int k = 0; k < 32; ++k) acc2[k] = b2[og * 32 + k];
  for (int c2 = 0; c2 < 64; ++c2) {
    float2 hv = *(const float2*)&lds[nl * 134 + 2 * c2];
    const float* wr0 = w2t + (2 * c2) * CH + og * 32;
    const float* wr1 = wr0 + CH;
#pragma unroll
    for (int k = 0; k < 32; ++k) acc2[k] = fmaf(wr0[k], hv.x, acc2[k]);
#pragma unroll
    for (int k = 0; k < 32; ++k) acc2[k] = fmaf(wr1[k], hv.y, acc2[k]);
  }
#pragma unroll
  for (int k = 0; k < 32; ++k) {
    int o = og * 32 + k;
    out[((size_t)(b * CH + o)) * N_PTS + n0 + nl] = acc2[k];
  }
}

// ======================================================================
extern "C" void kernel_launch(void* const* d_in, const int* in_sizes, int n_in,
                              void* d_out, int out_size, void* d_ws, size_t ws_size,
                              hipStream_t stream) {
  const float* x     = (const float*)d_in[0];
  const float* xyz   = (const float*)d_in[1];
  const float* w1    = (const float*)d_in[2];
  const float* b1    = (const float*)d_in[3];
  const float* gamma = (const float*)d_in[4];
  const float* beta  = (const float*)d_in[5];
  const float* w2    = (const float*)d_in[6];
  const float* b2    = (const float*)d_in[7];
  float* out = (float*)d_out;

  float* W = (float*)d_ws;
  float4* xyz4 = (float4*)W;                               // 131072 f
  float4* nrm4 = (float4*)(W + 131072);                    // 131072 f
  float* w1t   = W + 262144;                               // 16896
  float* w2t   = W + 279040;                               // 16384
  float* stats = W + 295424;                               // 256
  float* scale = W + 295680;                               // 128
  float* shift = W + 295808;                               // 128
  unsigned short* nidx = (unsigned short*)(W + 295936);    // 327680 f worth
  int* counts    = (int*)(W + 623616);                     // 256000
  int* cellStart = (int*)(W + 879616);                     // 256001
  int* cursor    = (int*)(W + 1135620);                    // 256000
  float4* spts   = (float4*)(W + 1391620);                 // 131072 f (16B aligned)
  int* sidx      = (int*)(W + 1522692);                    // 32768

  zero_kernel<<<(NCELLT + 255) / 256, 256, 0, stream>>>(counts, cursor, stats);
  prep_kernel<<<128, 256, 0, stream>>>(xyz, w1, w2, xyz4, w1t, w2t, counts);
  scan_kernel<<<1, 1024, 0, stream>>>(counts, cellStart);
  scatter_kernel<<<128, 256, 0, stream>>>(xyz4, cellStart, cursor, spts, sidx);
  knn_grid_kernel<<<BATCH * N_PTS / QPB, 256, 0, stream>>>(spts, sidx, cellStart, nidx);
  normals_kernel<<<BATCH * N_PTS / 256, 256, 0, stream>>>(xyz4, nidx, nrm4);
  gemm1_stats_kernel<<<BATCH * N_PTS / 64, 256, 0, stream>>>(x, nrm4, w1t, b1, stats, stats + 128);
  bn_finalize_kernel<<<1, 128, 0, stream>>>(stats, stats + 128, gamma, beta, scale, shift);
  fused_out_kernel<<<BATCH * N_PTS / 64, 256, 0, stream>>>(x, nrm4, w1t, b1, w2t, b2, scale, shift, out);
}

// Round 8
// 1300.746 us; speedup vs baseline: 5.3538x; 1.5875x over previous
//
#include <hip/hip_runtime.h>
#include <math.h>

#define N_PTS 8192
#define BATCH 4
#define CH 128
#define KNN 20
#define CAP 248
#define QPB 32            // queries per knn block
#define GDIM 40
#define GX0 -5.2f
#define GH 0.26f
#define GINVH (1.0f/0.26f)
#define NCELL (GDIM*GDIM*GDIM)            // 64000 per batch
#define NCELLT (NCELL*BATCH)              // 256000 total

// ======================================================================
// LAPACK ssyevd emulation for 3x3 symmetric (lower), SINGLE precision.
// (verified passing rounds 2-7 — do not perturb numerics)
// ======================================================================

__device__ __forceinline__ float slapy2f(float x, float y) {
#pragma clang fp contract(off)
  float ax = fabsf(x), ay = fabsf(y);
  float w = fmaxf(ax, ay), z = fminf(ax, ay);
  if (z == 0.0f) return w;
  float t = z / w;
  return w * sqrtf(1.0f + t * t);
}

__device__ __forceinline__ void slartgf(float f, float g, float* cs, float* sn, float* r) {
#pragma clang fp contract(off)
  if (g == 0.0f) { *cs = 1.0f; *sn = 0.0f; *r = f; }
  else if (f == 0.0f) { *cs = 0.0f; *sn = copysignf(1.0f, g); *r = fabsf(g); }
  else {
    float f1 = fabsf(f);
    float d = sqrtf(f * f + g * g);
    *cs = f1 / d;
    *r = copysignf(d, f);
    *sn = g / (*r);
  }
}

__device__ void slaev2f(float a, float b, float c, float* rt1, float* rt2,
                        float* cs1, float* sn1) {
#pragma clang fp contract(off)
  float sm = a + c, df = a - c, adf = fabsf(df);
  float tb = b + b, ab = fabsf(tb);
  float acmx, acmn;
  if (fabsf(a) > fabsf(c)) { acmx = a; acmn = c; } else { acmx = c; acmn = a; }
  float rt;
  if (adf > ab)      { float q = ab / adf;  rt = adf * sqrtf(1.0f + q * q); }
  else if (adf < ab) { float q = adf / ab;  rt = ab * sqrtf(1.0f + q * q); }
  else               rt = ab * sqrtf(2.0f);
  int sgn1;
  if (sm < 0.0f)      { *rt1 = 0.5f * (sm - rt); sgn1 = -1; *rt2 = (acmx / *rt1) * acmn - (b / *rt1) * b; }
  else if (sm > 0.0f) { *rt1 = 0.5f * (sm + rt); sgn1 = 1;  *rt2 = (acmx / *rt1) * acmn - (b / *rt1) * b; }
  else                { *rt1 = 0.5f * rt; *rt2 = -0.5f * rt; sgn1 = 1; }
  float cs; int sgn2;
  if (df >= 0.0f) { cs = df + rt; sgn2 = 1; } else { cs = df - rt; sgn2 = -1; }
  float acs = fabsf(cs);
  if (acs > ab) {
    float ct = -tb / cs;
    *sn1 = 1.0f / sqrtf(1.0f + ct * ct);
    *cs1 = ct * (*sn1);
  } else {
    if (ab == 0.0f) { *cs1 = 1.0f; *sn1 = 0.0f; }
    else {
      float tn = -cs / tb;
      *cs1 = 1.0f / sqrtf(1.0f + tn * tn);
      *sn1 = tn * (*cs1);
    }
  }
  if (sgn1 == sgn2) { float tn = *cs1; *cs1 = -(*sn1); *sn1 = tn; }
}

__device__ void eigh3_smallest(float a00, float a10, float a20,
                               float a11, float a21, float a22, float evec[3]) {
#pragma clang fp contract(off)
  float d[3], e[2], tau = 0.0f, v2 = 0.0f;
  d[0] = a00;
  {
    float xnorm = sqrtf(a20 * a20);
    if (xnorm == 0.0f) {
      tau = 0.0f; v2 = 0.0f;
      e[0] = a10; d[1] = a11; e[1] = a21; d[2] = a22;
    } else {
      float alpha = a10;
      float beta = -copysignf(slapy2f(alpha, xnorm), alpha);
      tau = (beta - alpha) / beta;
      float invs = 1.0f / (alpha - beta);
      v2 = a20 * invs;
      e[0] = beta;
      float y0 = tau * a11;
      float y1 = tau * a21;
      y0 = y0 + tau * (a21 * v2);
      y1 = y1 + (tau * v2) * a22;
      float dot = y0 + y1 * v2;
      float al = (-0.5f * tau) * dot;
      float w0 = y0 + al;
      float w1 = y1 + al * v2;
      a11 = (a11 - w0) - w0;
      a21 = (a21 - v2 * w0) - w1;
      a22 = (a22 - v2 * w1) - w1 * v2;
      d[1] = a11; e[1] = a21; d[2] = a22;
    }
  }

  float z[3][3] = {{1.0f,0.0f,0.0f},{0.0f,1.0f,0.0f},{0.0f,0.0f,1.0f}};
  const float eps = 5.9604644775390625e-08f;
  const float eps2 = 3.5527136788005009e-15f;
  const float safmin = 1.1754943508222875e-38f;
  int nmaxit = 90, jtot = 0;
  int l1 = 0;
  int l, m, lend, lsv, lendsv;
  float p, g, r, c, s, f, b_, rt1, rt2, tst;
  float wc[2], wsn[2];

outer_loop:
  if (l1 > 2) goto sorting;
  if (l1 > 0) e[l1 - 1] = 0.0f;
  {
    int mm;
    for (mm = l1; mm <= 1; ++mm) {
      tst = fabsf(e[mm]);
      if (tst == 0.0f) break;
      if (tst <= (sqrtf(fabsf(d[mm])) * sqrtf(fabsf(d[mm + 1]))) * eps) { e[mm] = 0.0f; break; }
    }
    m = (mm > 1) ? 2 : mm;
  }
  l = l1; lsv = l; lend = m; lendsv = lend; l1 = m + 1;
  if (lend == l) goto outer_loop;
  {
    float an = 0.0f;
    for (int i2 = l; i2 <= lend; ++i2) an = fmaxf(an, fabsf(d[i2]));
    for (int i2 = l; i2 < lend; ++i2) an = fmaxf(an, fabsf(e[i2]));
    if (an == 0.0f) goto outer_loop;
  }
  if (fabsf(d[lend]) < fabsf(d[l])) { lend = lsv; l = lendsv; }

  if (lend > l) {
ql40:
    if (l != lend) {
      for (m = l; m <= lend - 1; ++m) {
        tst = e[m] * e[m];
        if (tst <= (eps2 * fabsf(d[m])) * fabsf(d[m + 1]) + safmin) goto ql60;
      }
    }
    m = lend;
ql60:
    if (m < lend) e[m] = 0.0f;
    p = d[l];
    if (m == l) goto ql80;
    if (m == l + 1) {
      slaev2f(d[l], e[l], d[l + 1], &rt1, &rt2, &c, &s);
      for (int i2 = 0; i2 < 3; ++i2) {
        float temp = z[i2][l + 1];
        z[i2][l + 1] = c * temp - s * z[i2][l];
        z[i2][l]     = s * temp + c * z[i2][l];
      }
      d[l] = rt1; d[l + 1] = rt2; e[l] = 0.0f;
      l += 2;
      if (l <= lend) goto ql40;
      goto done140;
    }
    if (jtot == nmaxit) goto done140;
    jtot++;
    g = (d[l + 1] - p) / (2.0f * e[l]);
    r = slapy2f(g, 1.0f);
    g = d[m] - p + e[l] / (g + copysignf(r, g));
    s = 1.0f; c = 1.0f; p = 0.0f;
    for (int i2 = m - 1; i2 >= l; --i2) {
      f = s * e[i2]; b_ = c * e[i2];
      slartgf(g, f, &c, &s, &r);
      if (i2 != m - 1) e[i2 + 1] = r;
      g = d[i2 + 1] - p;
      r = (d[i2] - g) * s + 2.0f * c * b_;
      p = s * r;
      d[i2 + 1] = g + p;
      g = c * r - b_;
      wc[i2] = c; wsn[i2] = -s;
    }
    for (int j = m - 1; j >= l; --j) {
      float ct = wc[j], st = wsn[j];
      for (int i2 = 0; i2 < 3; ++i2) {
        float temp = z[i2][j + 1];
        z[i2][j + 1] = ct * temp - st * z[i2][j];
        z[i2][j]     = st * temp + ct * z[i2][j];
      }
    }
    d[l] -= p;
    e[l] = g;
    goto ql40;
ql80:
    d[l] = p;
    l += 1;
    if (l <= lend) goto ql40;
    goto done140;
  } else {
qr90:
    if (l != lend) {
      for (m = l; m >= lend + 1; --m) {
        tst = e[m - 1] * e[m - 1];
        if (tst <= (eps2 * fabsf(d[m])) * fabsf(d[m - 1]) + safmin) goto qr110;
      }
    }
    m = lend;
qr110:
    if (m > lend) e[m - 1] = 0.0f;
    p = d[l];
    if (m == l) goto qr130;
    if (m == l - 1) {
      slaev2f(d[l - 1], e[l - 1], d[l], &rt1, &rt2, &c, &s);
      for (int i2 = 0; i2 < 3; ++i2) {
        float temp = z[i2][l];
        z[i2][l]     = c * temp - s * z[i2][l - 1];
        z[i2][l - 1] = s * temp + c * z[i2][l - 1];
      }
      d[l - 1] = rt1; d[l] = rt2; e[l - 1] = 0.0f;
      l -= 2;
      if (l >= lend) goto qr90;
      goto done140;
    }
    if (jtot == nmaxit) goto done140;
    jtot++;
    g = (d[l - 1] - p) / (2.0f * e[l - 1]);
    r = slapy2f(g, 1.0f);
    g = d[m] - p + e[l - 1] / (g + copysignf(r, g));
    s = 1.0f; c = 1.0f; p = 0.0f;
    for (int i2 = m; i2 <= l - 1; ++i2) {
      f = s * e[i2]; b_ = c * e[i2];
      slartgf(g, f, &c, &s, &r);
      if (i2 != m) e[i2 - 1] = r;
      g = d[i2] - p;
      r = (d[i2 + 1] - g) * s + 2.0f * c * b_;
      p = s * r;
      d[i2] = g + p;
      g = c * r - b_;
      wc[i2] = c; wsn[i2] = s;
    }
    for (int j = m; j <= l - 1; ++j) {
      float ct = wc[j], st = wsn[j];
      for (int i2 = 0; i2 < 3; ++i2) {
        float temp = z[i2][j + 1];
        z[i2][j + 1] = ct * temp - st * z[i2][j];
        z[i2][j]     = st * temp + ct * z[i2][j];
      }
    }
    d[l] -= p;
    e[l - 1] = g;
    goto qr90;
qr130:
    d[l] = p;
    l -= 1;
    if (l >= lend) goto qr90;
    goto done140;
  }
done140:
  if (jtot < nmaxit) goto outer_loop;
sorting:
  for (int ii = 1; ii <= 2; ++ii) {
    int i_ = ii - 1, k = i_;
    p = d[i_];
    for (int j = ii; j <= 2; ++j) if (d[j] < p) { k = j; p = d[j]; }
    if (k != i_) {
      d[k] = d[i_]; d[i_] = p;
      for (int i2 = 0; i2 < 3; ++i2) { float tz = z[i2][i_]; z[i2][i_] = z[i2][k]; z[i2][k] = tz; }
    }
  }
  {
    float z10 = z[1][0], z20 = z[2][0];
    float sum = z10 + v2 * z20;
    evec[0] = z[0][0];
    evec[1] = z10 - tau * sum;
    evec[2] = z20 - tau * sum * v2;
  }
}

// ======================================================================
__device__ __forceinline__ float qdist(const float4 qv, const float4 cv) {
  float dot = fmaf(qv.x, cv.x, fmaf(qv.y, cv.y, qv.z * cv.z));
  return fmaf(-2.0f, dot, qv.w + cv.w);
}

__device__ __forceinline__ unsigned int distbits(float dist) {
  unsigned int du = __float_as_uint(dist);
  return (du & 0x80000000u) ? ~du : (du | 0x80000000u);
}

__device__ __forceinline__ int cell1(float v) {
  return min(GDIM - 1, max(0, (int)floorf((v - GX0) * GINVH)));
}

// ======================================================================
// Kernel A: zero cell counts/cursors + stats
// ======================================================================
__global__ __launch_bounds__(256) void zero_kernel(int* __restrict__ counts,
                                                   int* __restrict__ cursor,
                                                   float* __restrict__ stats) {
  int i = blockIdx.x * 256 + threadIdx.x;
  if (i < NCELLT) { counts[i] = 0; cursor[i] = 0; }
  if (i < 256) stats[i] = 0.0f;
}

// ======================================================================
// Kernel B: prep — pack xyz4 + cell histogram + transpose w1/w2
// ======================================================================
__global__ __launch_bounds__(256) void prep_kernel(const float* __restrict__ xyz,
                                                   const float* __restrict__ w1,
                                                   const float* __restrict__ w2,
                                                   float4* __restrict__ xyz4,
                                                   float* __restrict__ w1t,
                                                   float* __restrict__ w2t,
                                                   int* __restrict__ counts) {
  int idx = blockIdx.x * 256 + threadIdx.x;
  if (idx < BATCH * N_PTS) {
    float x = xyz[idx * 3], y = xyz[idx * 3 + 1], zz = xyz[idx * 3 + 2];
    float sq = fmaf(zz, zz, fmaf(y, y, x * x));
    xyz4[idx] = make_float4(x, y, zz, sq);
    int batch = idx >> 13;
    int cid = batch * NCELL + (cell1(x) * GDIM + cell1(y)) * GDIM + cell1(zz);
    atomicAdd(&counts[cid], 1);
  }
  if (idx < 132 * CH) {
    int cc = idx >> 7, o = idx & 127;
    w1t[idx] = (cc < 131) ? w1[o * 131 + cc] : 0.0f;
  }
  if (idx < CH * CH) {
    int cc = idx >> 7, o = idx & 127;
    w2t[idx] = w2[o * CH + cc];
  }
}

// ======================================================================
// Kernel C: exclusive scan of counts -> cellStart (single block)
// ======================================================================
__global__ __launch_bounds__(1024) void scan_kernel(const int* __restrict__ counts,
                                                    int* __restrict__ cellStart) {
  __shared__ int part[1024];
  const int tid = threadIdx.x;
  const int per = NCELLT / 1024;          // 250
  const int i0 = tid * per;
  int s = 0;
  for (int j = 0; j < per; ++j) s += counts[i0 + j];
  part[tid] = s;
  __syncthreads();
  for (int off = 1; off < 1024; off <<= 1) {
    int v = (tid >= off) ? part[tid - off] : 0;
    __syncthreads();
    part[tid] += v;
    __syncthreads();
  }
  int run = part[tid] - s;                // exclusive base
  for (int j = 0; j < per; ++j) { cellStart[i0 + j] = run; run += counts[i0 + j]; }
  if (tid == 1023) cellStart[NCELLT] = run;
}

// ======================================================================
// Kernel D: scatter points into cell-sorted order
// ======================================================================
__global__ __launch_bounds__(256) void scatter_kernel(const float4* __restrict__ xyz4,
                                                      const int* __restrict__ cellStart,
                                                      int* __restrict__ cursor,
                                                      float4* __restrict__ spts,
                                                      int* __restrict__ sidx) {
  int idx = blockIdx.x * 256 + threadIdx.x;
  if (idx < BATCH * N_PTS) {
    float4 v = xyz4[idx];
    int batch = idx >> 13;
    int cid = batch * NCELL + (cell1(v.x) * GDIM + cell1(v.y)) * GDIM + cell1(v.z);
    int pos = cellStart[cid] + atomicAdd(&cursor[cid], 1);
    spts[pos] = v;
    sidx[pos] = idx & (N_PTS - 1);
  }
}

// ======================================================================
// Kernel E: exact grid-pruned 20-NN. 256 thr = 32 queries x 8 subs.
//  Bound: z-stratified point partition (p ≡ sub mod 8) — unbiased 1/8
//         samples per sub; per-sub exact 3-smallest; grow s=1..6 while
//         Σ min(seen,3) < 20; cap -> index-chunked full-scan bound.
//         Tq = 20th smallest of 24 (>=20 distinct cands <= Tq => exact).
//  Exact: columns with min-dist <= Tprune (border one-sided), z-runs;
//         collect dist<=Tq (CAP=248). Overflow (rank(Tq)>CAP, ~never):
//         PARALLEL fallback — 8 subs each keep exact top-20 of their own
//         1024-pt index chunk (top-20 ⊆ union, partition argument), append
//         160 keys to lst, reset count. Common 8-lane selection finishes.
// ======================================================================
__global__ __launch_bounds__(256) void knn_grid_kernel(const float4* __restrict__ spts,
                                                       const int* __restrict__ sidx,
                                                       const int* __restrict__ cellStart,
                                                       unsigned short* __restrict__ nidx) {
  __shared__ unsigned long long lst[QPB * (CAP + 2)];
  __shared__ unsigned int qcnt[QPB];
  __shared__ unsigned int qover[QPB];

  const int t = threadIdx.x;
  const int qg = t >> 3, sub = t & 7;
  const int lane = t & 63;
  const int gpos = blockIdx.x * QPB + qg;
  const int batch = gpos >> 13;
  if (sub == 0) { qcnt[qg] = 0; qover[qg] = 0; }

  const float4 qv = spts[gpos];
  const int qidx = sidx[gpos];
  const int cbase = batch * NCELL;
  const int cx = cell1(qv.x), cy = cell1(qv.y), cz = cell1(qv.z);

  // ---- bound phase: per-sub exact 3-smallest over z-stratified samples ----
  float a0 = INFINITY, a1 = INFINITY, a2 = INFINITY;
  {
    bool ok = false;
    for (int s = 1; s <= 6 && !ok; ++s) {
      a0 = INFINITY; a1 = INFINITY; a2 = INFINITY;
      int seen = 0;
      int xlo = max(0, cx - s), xhi = min(GDIM - 1, cx + s);
      int ylo = max(0, cy - s), yhi = min(GDIM - 1, cy + s);
      int zlo = max(0, cz - s), zhi = min(GDIM - 1, cz + s);
      for (int i = xlo; i <= xhi; ++i)
        for (int j = ylo; j <= yhi; ++j) {
          int rb = cbase + (i * GDIM + j) * GDIM;
          int p0 = cellStart[rb + zlo], p1 = cellStart[rb + zhi + 1];
          for (int p = p0 + ((sub - p0) & 7); p < p1; p += 8) {
            float dist = qdist(qv, spts[p]);
            ++seen;
            float u0 = fmaxf(a0, dist); a0 = fminf(a0, dist);
            float u1 = fmaxf(a1, u0);   a1 = fminf(a1, u0);
            a2 = fminf(a2, u1);
          }
        }
      int tot = min(seen, 3);
      tot += __shfl_xor(tot, 1, 64);
      tot += __shfl_xor(tot, 2, 64);
      tot += __shfl_xor(tot, 4, 64);
      ok = (tot >= 20);
    }
    if (!ok) {
      // deep-tail queries: index-chunked full scan (spatially random => tight)
      a0 = INFINITY; a1 = INFINITY; a2 = INFINITY;
      const int pb = batch * N_PTS + sub * (N_PTS / 8);
      for (int p = pb; p < pb + N_PTS / 8; ++p) {
        float dist = qdist(qv, spts[p]);
        float u0 = fmaxf(a0, dist); a0 = fminf(a0, dist);
        float u1 = fmaxf(a1, u0);   a1 = fminf(a1, u0);
        a2 = fminf(a2, u1);
      }
    }
  }

  // ---- Tq = 20th smallest of 24 = 5th largest (5 rounds argmax-remove) ----
  float Tq = INFINITY;
  {
    int rem = 0;
    const int gb = lane & 56;
    for (int r = 0; r < 5; ++r) {
      float mymax = (rem == 0) ? a2 : (rem == 1) ? a1 : (rem == 2) ? a0 : -INFINITY;
      unsigned long long key = ((unsigned long long)distbits(mymax) << 3) | (unsigned int)sub;
      unsigned long long o;
      o = __shfl_xor(key, 1, 64); key = (o > key) ? o : key;
      o = __shfl_xor(key, 2, 64); key = (o > key) ? o : key;
      o = __shfl_xor(key, 4, 64); key = (o > key) ? o : key;
      int wl = (int)(key & 7u);
      float v = __shfl(mymax, gb | wl, 64);
      if (wl == sub) rem++;
      if (r == 4) Tq = v;
    }
  }

  // ---- exact phase ----
  const float Tprune = Tq * 1.0001f + 1e-9f;
  const float r = sqrtf(Tprune) * 1.0002f + 1e-7f;
  const int cxlo = min(GDIM - 1, max(0, (int)floorf((qv.x - r - GX0) * GINVH)));
  const int cxhi = min(GDIM - 1, max(0, (int)floorf((qv.x + r - GX0) * GINVH)));
  const int cylo = min(GDIM - 1, max(0, (int)floorf((qv.y - r - GX0) * GINVH)));
  const int cyhi = min(GDIM - 1, max(0, (int)floorf((qv.y + r - GX0) * GINVH)));
  int m2 = 0;
  for (int i = cxlo; i <= cxhi; ++i) {
    float lox = fmaf((float)i, GH, GX0), hix = lox + GH;
    float dxl = lox - qv.x; if (i == 0) dxl = -1e30f;        // border: one-sided
    float dxh = qv.x - hix; if (i == GDIM - 1) dxh = -1e30f;
    float dx = fmaxf(0.0f, fmaxf(dxl, dxh));
    float dx2 = dx * dx;
    for (int j = cylo; j <= cyhi; ++j) {
      if (((m2++) & 7) != sub) continue;
      float loy = fmaf((float)j, GH, GX0), hiy = loy + GH;
      float dyl = loy - qv.y; if (j == 0) dyl = -1e30f;
      float dyh = qv.y - hiy; if (j == GDIM - 1) dyh = -1e30f;
      float dy = fmaxf(0.0f, fmaxf(dyl, dyh));
      float d2 = fmaf(dy, dy, dx2);
      if (d2 > Tprune) continue;
      float rz = sqrtf(fmaxf(0.0f, Tprune - d2)) * 1.0002f + 1e-7f;
      int klo = min(GDIM - 1, max(0, (int)floorf((qv.z - rz - GX0) * GINVH)));
      int khi = min(GDIM - 1, max(0, (int)floorf((qv.z + rz - GX0) * GINVH)));
      int rb = cbase + (i * GDIM + j) * GDIM;
      int p0 = cellStart[rb + klo], p1 = cellStart[rb + khi + 1];
      for (int p = p0; p < p1; ++p) {
        float4 cv = spts[p];
        float dist = qdist(qv, cv);
        if (dist <= Tq) {
          unsigned long long key = ((unsigned long long)distbits(dist) << 32)
                                 | (unsigned int)sidx[p];
          unsigned int pos = atomicAdd(&qcnt[qg], 1u);
          if (pos < CAP) lst[qg * (CAP + 2) + pos] = key;
          else qover[qg] = 1u;
        }
      }
    }
  }

  // ---- overflow (~never): PARALLEL fallback, 8 subs x 1024-pt chunks ----
  if (qover[qg]) {
    if (sub == 0) qcnt[qg] = 0;       // same wave: in-order before appends
    unsigned long long best[KNN];
#pragma unroll
    for (int j = 0; j < KNN; ++j) best[j] = ~0ULL;
    const int pb = batch * N_PTS + sub * (N_PTS / 8);
    for (int m = pb; m < pb + N_PTS / 8; ++m) {
      float dist = qdist(qv, spts[m]);
      unsigned long long pk = ((unsigned long long)distbits(dist) << 32)
                            | (unsigned int)sidx[m];
      if (pk < best[KNN - 1]) {
        best[KNN - 1] = pk;
#pragma unroll
        for (int j = KNN - 1; j > 0; --j) {
          unsigned long long xx = best[j - 1], yy = best[j];
          bool sw = yy < xx;
          best[j - 1] = sw ? yy : xx;
          best[j]     = sw ? xx : yy;
        }
      }
    }
#pragma unroll
    for (int j = 0; j < KNN; ++j) {
      unsigned int pos = atomicAdd(&qcnt[qg], 1u);
      lst[qg * (CAP + 2) + pos] = best[j];   // 160 <= CAP
    }
  }

  // ---- common selection (8 lanes per query) ----
  unsigned int n = qcnt[qg]; if (n > CAP) n = CAP;
  unsigned short* oq = nidx + ((size_t)(batch * N_PTS + qidx)) * KNN;
  for (int rr = 0; rr < KNN; ++rr) {
    unsigned long long best = ~0ULL; int bslot = 0;
    for (unsigned int s2 = sub; s2 < n; s2 += 8) {
      unsigned long long v = lst[qg * (CAP + 2) + s2];
      if (v < best) { best = v; bslot = (int)s2; }
    }
#pragma unroll
    for (int mm = 1; mm < 8; mm <<= 1) {
      unsigned long long ob = __shfl_xor(best, mm, 64);
      int obs = __shfl_xor(bslot, mm, 64);
      if (ob < best) { best = ob; bslot = obs; }
    }
    if ((bslot & 7) == sub) lst[qg * (CAP + 2) + bslot] = ~0ULL;
    if (sub == 0) oq[rr] = (unsigned short)(best & 0xffffu);
  }
}

// ======================================================================
// Kernel F: covariance (sorted order) + eigh -> normals
// ======================================================================
__global__ __launch_bounds__(256) void normals_kernel(const float4* __restrict__ xyz4,
                                                      const unsigned short* __restrict__ nidx,
                                                      float4* __restrict__ nrm4) {
  int gid = blockIdx.x * 256 + threadIdx.x;
  int batch = gid >> 13, q = gid & (N_PTS - 1);
  const float4* __restrict__ xb = xyz4 + batch * N_PTS;
  const float4 qv = xb[q];
  const unsigned short* iq = nidx + (size_t)gid * KNN;
  float c00, c01, c02, c11, c12, c22;
  {
#pragma clang fp contract(off)
    c00 = 0.f; c01 = 0.f; c02 = 0.f; c11 = 0.f; c12 = 0.f; c22 = 0.f;
    for (int j = 0; j < KNN; ++j) {
      float4 pv = xb[iq[j]];
      float dx = pv.x - qv.x, dy = pv.y - qv.y, dz = pv.z - qv.z;
      c00 = c00 + dx * dx; c01 = c01 + dx * dy; c02 = c02 + dx * dz;
      c11 = c11 + dy * dy; c12 = c12 + dy * dz; c22 = c22 + dz * dz;
    }
  }
  float ev[3];
  eigh3_smallest(c00, c01, c02, c11, c12, c22, ev);
  nrm4[gid] = make_float4(ev[0], ev[1], ev[2], 0.0f);
}

// ======================================================================
// Kernel G: GEMM1 + BN stats
// ======================================================================
__global__ __launch_bounds__(256) void gemm1_stats_kernel(const float* __restrict__ x,
                                                          const float4* __restrict__ nrm4,
                                                          const float* __restrict__ w1t,
                                                          const float* __restrict__ b1,
                                                          float* __restrict__ sums,
                                                          float* __restrict__ sumsq) {
  __shared__ float lds[64 * 134];
  const int t = threadIdx.x;
  const int b = blockIdx.x >> 7;
  const int n0 = (blockIdx.x & 127) << 6;
  for (int idx = t; idx < CH * 64; idx += 256) {
    int cc = idx >> 6, nl = idx & 63;
    lds[nl * 134 + cc] = x[((size_t)(b * CH + cc)) * N_PTS + n0 + nl];
  }
  if (t < 64) {
    float4 nv = nrm4[b * N_PTS + n0 + t];
    lds[t * 134 + 128] = nv.x; lds[t * 134 + 129] = nv.y;
    lds[t * 134 + 130] = nv.z; lds[t * 134 + 131] = 0.0f;
  }
  __syncthreads();

  const int og = __builtin_amdgcn_readfirstlane(t >> 6);
  const int nl = t & 63;
  float acc[32];
#pragma unroll
  for (int k = 0; k < 32; ++k) acc[k] = b1[og * 32 + k];
  for (int c2 = 0; c2 < 66; ++c2) {
    float2 xv = *(const float2*)&lds[nl * 134 + 2 * c2];
    const float* wr0 = w1t + (2 * c2) * CH + og * 32;
    const float* wr1 = wr0 + CH;
#pragma unroll
    for (int k = 0; k < 32; ++k) acc[k] = fmaf(wr0[k], xv.x, acc[k]);
#pragma unroll
    for (int k = 0; k < 32; ++k) acc[k] = fmaf(wr1[k], xv.y, acc[k]);
  }
  __syncthreads();
#pragma unroll
  for (int k2 = 0; k2 < 16; ++k2)
    *(float2*)&lds[nl * 134 + og * 32 + 2 * k2] = make_float2(acc[2 * k2], acc[2 * k2 + 1]);
  __syncthreads();
  {
    int cc = t & 127, hf = t >> 7;
    float sm = 0.f, sq = 0.f;
    for (int rr = hf * 32; rr < hf * 32 + 32; ++rr) {
      float v = lds[rr * 134 + cc];
      sm += v; sq = fmaf(v, v, sq);
    }
    atomicAdd(&sums[cc], sm);
    atomicAdd(&sumsq[cc], sq);
  }
}

// ======================================================================
// Kernel H: finalize BN scale/shift
// ======================================================================
__global__ void bn_finalize_kernel(const float* __restrict__ sums, const float* __restrict__ sumsq,
                                   const float* __restrict__ gamma, const float* __restrict__ beta,
                                   float* __restrict__ scale, float* __restrict__ shift) {
  int c = threadIdx.x;
  if (c < CH) {
    const double cnt = (double)(BATCH * N_PTS);
    double mean = (double)sums[c] / cnt;
    double var = (double)sumsq[c] / cnt - mean * mean;
    double inv = 1.0 / sqrt(var + 1e-5);
    double sc = (double)gamma[c] * inv;
    scale[c] = (float)sc;
    shift[c] = (float)((double)beta[c] - mean * sc);
  }
}

// ======================================================================
// Kernel I: fused GEMM1 (recompute) + BN + ReLU + GEMM2 -> out
// ======================================================================
__global__ __launch_bounds__(256) void fused_out_kernel(const float* __restrict__ x,
                                                        const float4* __restrict__ nrm4,
                                                        const float* __restrict__ w1t,
                                                        const float* __restrict__ b1,
                                                        const float* __restrict__ w2t,
                                                        const float* __restrict__ b2,
                                                        const float* __restrict__ scale,
                                                        const float* __restrict__ shift,
                                                        float* __restrict__ out) {
  __shared__ float lds[64 * 134];
  const int t = threadIdx.x;
  const int b = blockIdx.x >> 7;
  const int n0 = (blockIdx.x & 127) << 6;
  for (int idx = t; idx < CH * 64; idx += 256) {
    int cc = idx >> 6, nl = idx & 63;
    lds[nl * 134 + cc] = x[((size_t)(b * CH + cc)) * N_PTS + n0 + nl];
  }
  if (t < 64) {
    float4 nv = nrm4[b * N_PTS + n0 + t];
    lds[t * 134 + 128] = nv.x; lds[t * 134 + 129] = nv.y;
    lds[t * 134 + 130] = nv.z; lds[t * 134 + 131] = 0.0f;
  }
  __syncthreads();

  const int og = __builtin_amdgcn_readfirstlane(t >> 6);
  const int nl = t & 63;
  float acc[32];
#pragma unroll
  for (int k = 0; k < 32; ++k) acc[k] = b1[og * 32 + k];
  for (int c2 = 0; c2 < 66; ++c2) {
    float2 xv = *(const float2*)&lds[nl * 134 + 2 * c2];
    const float* wr0 = w1t + (2 * c2) * CH + og * 32;
    const float* wr1 = wr0 + CH;
#pragma unroll
    for (int k = 0; k < 32; ++k) acc[k] = fmaf(wr0[k], xv.x, acc[k]);
#pragma unroll
    for (int k = 0; k < 32; ++k) acc[k] = fmaf(wr1[k], xv.y, acc[k]);
  }
#pragma unroll
  for (int k = 0; k < 32; ++k) {
    float sc = scale[og * 32 + k], sh = shift[og * 32 + k];
    acc[k] = fmaxf(fmaf(acc[k], sc, sh), 0.0f);
  }
  __syncthreads();
#pragma unroll
  for (int k2 = 0; k2 < 16; ++k2)
    *(float2*)&lds[nl * 134 + og * 32 + 2 * k2] = make_float2(acc[2 * k2], acc[2 * k2 + 1]);
  __syncthreads();

  float acc2[32];
#pragma unroll
  for (int k = 0; k < 32; ++k) acc2[k] = b2[og * 32 + k];
  for (int c2 = 0; c2 < 64; ++c2) {
    float2 hv = *(const float2*)&lds[nl * 134 + 2 * c2];
    const float* wr0 = w2t + (2 * c2) * CH + og * 32;
    const float* wr1 = wr0 + CH;
#pragma unroll
    for (int k = 0; k < 32; ++k) acc2[k] = fmaf(wr0[k], hv.x, acc2[k]);
#pragma unroll
    for (int k = 0; k < 32; ++k) acc2[k] = fmaf(wr1[k], hv.y, acc2[k]);
  }
#pragma unroll
  for (int k = 0; k < 32; ++k) {
    int o = og * 32 + k;
    out[((size_t)(b * CH + o)) * N_PTS + n0 + nl] = acc2[k];
  }
}

// ======================================================================
extern "C" void kernel_launch(void* const* d_in, const int* in_sizes, int n_in,
                              void* d_out, int out_size, void* d_ws, size_t ws_size,
                              hipStream_t stream) {
  const float* x     = (const float*)d_in[0];
  const float* xyz   = (const float*)d_in[1];
  const float* w1    = (const float*)d_in[2];
  const float* b1    = (const float*)d_in[3];
  const float* gamma = (const float*)d_in[4];
  const float* beta  = (const float*)d_in[5];
  const float* w2    = (const float*)d_in[6];
  const float* b2    = (const float*)d_in[7];
  float* out = (float*)d_out;

  float* W = (float*)d_ws;
  float4* xyz4 = (float4*)W;                               // 131072 f
  float4* nrm4 = (float4*)(W + 131072);                    // 131072 f
  float* w1t   = W + 262144;                               // 16896
  float* w2t   = W + 279040;                               // 16384
  float* stats = W + 295424;                               // 256
  float* scale = W + 295680;                               // 128
  float* shift = W + 295808;                               // 128
  unsigned short* nidx = (unsigned short*)(W + 295936);    // 327680 f worth
  int* counts    = (int*)(W + 623616);                     // 256000
  int* cellStart = (int*)(W + 879616);                     // 256001
  int* cursor    = (int*)(W + 1135620);                    // 256000
  float4* spts   = (float4*)(W + 1391620);                 // 131072 f (16B aligned)
  int* sidx      = (int*)(W + 1522692);                    // 32768

  zero_kernel<<<(NCELLT + 255) / 256, 256, 0, stream>>>(counts, cursor, stats);
  prep_kernel<<<128, 256, 0, stream>>>(xyz, w1, w2, xyz4, w1t, w2t, counts);
  scan_kernel<<<1, 1024, 0, stream>>>(counts, cellStart);
  scatter_kernel<<<128, 256, 0, stream>>>(xyz4, cellStart, cursor, spts, sidx);
  knn_grid_kernel<<<BATCH * N_PTS / QPB, 256, 0, stream>>>(spts, sidx, cellStart, nidx);
  normals_kernel<<<BATCH * N_PTS / 256, 256, 0, stream>>>(xyz4, nidx, nrm4);
  gemm1_stats_kernel<<<BATCH * N_PTS / 64, 256, 0, stream>>>(x, nrm4, w1t, b1, stats, stats + 128);
  bn_finalize_kernel<<<1, 128, 0, stream>>>(stats, stats + 128, gamma, beta, scale, shift);
  fused_out_kernel<<<BATCH * N_PTS / 64, 256, 0, stream>>>(x, nrm4, w1t, b1, w2t, b2, scale, shift, out);
}

// Round 9
// 591.827 us; speedup vs baseline: 11.7669x; 2.1978x over previous
//
#include <hip/hip_runtime.h>
#include <math.h>

#define N_PTS 8192
#define BATCH 4
#define CH 128
#define KNN 20
#define CAP 56

// ======================================================================
// LAPACK ssyevd emulation for 3x3 symmetric (lower), SINGLE precision.
// (verified passing rounds 2-8 — do not perturb numerics)
// ======================================================================

__device__ __forceinline__ float slapy2f(float x, float y) {
#pragma clang fp contract(off)
  float ax = fabsf(x), ay = fabsf(y);
  float w = fmaxf(ax, ay), z = fminf(ax, ay);
  if (z == 0.0f) return w;
  float t = z / w;
  return w * sqrtf(1.0f + t * t);
}

__device__ __forceinline__ void slartgf(float f, float g, float* cs, float* sn, float* r) {
#pragma clang fp contract(off)
  if (g == 0.0f) { *cs = 1.0f; *sn = 0.0f; *r = f; }
  else if (f == 0.0f) { *cs = 0.0f; *sn = copysignf(1.0f, g); *r = fabsf(g); }
  else {
    float f1 = fabsf(f);
    float d = sqrtf(f * f + g * g);
    *cs = f1 / d;
    *r = copysignf(d, f);
    *sn = g / (*r);
  }
}

__device__ void slaev2f(float a, float b, float c, float* rt1, float* rt2,
                        float* cs1, float* sn1) {
#pragma clang fp contract(off)
  float sm = a + c, df = a - c, adf = fabsf(df);
  float tb = b + b, ab = fabsf(tb);
  float acmx, acmn;
  if (fabsf(a) > fabsf(c)) { acmx = a; acmn = c; } else { acmx = c; acmn = a; }
  float rt;
  if (adf > ab)      { float q = ab / adf;  rt = adf * sqrtf(1.0f + q * q); }
  else if (adf < ab) { float q = adf / ab;  rt = ab * sqrtf(1.0f + q * q); }
  else               rt = ab * sqrtf(2.0f);
  int sgn1;
  if (sm < 0.0f)      { *rt1 = 0.5f * (sm - rt); sgn1 = -1; *rt2 = (acmx / *rt1) * acmn - (b / *rt1) * b; }
  else if (sm > 0.0f) { *rt1 = 0.5f * (sm + rt); sgn1 = 1;  *rt2 = (acmx / *rt1) * acmn - (b / *rt1) * b; }
  else                { *rt1 = 0.5f * rt; *rt2 = -0.5f * rt; sgn1 = 1; }
  float cs; int sgn2;
  if (df >= 0.0f) { cs = df + rt; sgn2 = 1; } else { cs = df - rt; sgn2 = -1; }
  float acs = fabsf(cs);
  if (acs > ab) {
    float ct = -tb / cs;
    *sn1 = 1.0f / sqrtf(1.0f + ct * ct);
    *cs1 = ct * (*sn1);
  } else {
    if (ab == 0.0f) { *cs1 = 1.0f; *sn1 = 0.0f; }
    else {
      float tn = -cs / tb;
      *cs1 = 1.0f / sqrtf(1.0f + tn * tn);
      *sn1 = tn * (*cs1);
    }
  }
  if (sgn1 == sgn2) { float tn = *cs1; *cs1 = -(*sn1); *sn1 = tn; }
}

__device__ void eigh3_smallest(float a00, float a10, float a20,
                               float a11, float a21, float a22, float evec[3]) {
#pragma clang fp contract(off)
  float d[3], e[2], tau = 0.0f, v2 = 0.0f;
  d[0] = a00;
  {
    float xnorm = sqrtf(a20 * a20);
    if (xnorm == 0.0f) {
      tau = 0.0f; v2 = 0.0f;
      e[0] = a10; d[1] = a11; e[1] = a21; d[2] = a22;
    } else {
      float alpha = a10;
      float beta = -copysignf(slapy2f(alpha, xnorm), alpha);
      tau = (beta - alpha) / beta;
      float invs = 1.0f / (alpha - beta);
      v2 = a20 * invs;
      e[0] = beta;
      float y0 = tau * a11;
      float y1 = tau * a21;
      y0 = y0 + tau * (a21 * v2);
      y1 = y1 + (tau * v2) * a22;
      float dot = y0 + y1 * v2;
      float al = (-0.5f * tau) * dot;
      float w0 = y0 + al;
      float w1 = y1 + al * v2;
      a11 = (a11 - w0) - w0;
      a21 = (a21 - v2 * w0) - w1;
      a22 = (a22 - v2 * w1) - w1 * v2;
      d[1] = a11; e[1] = a21; d[2] = a22;
    }
  }

  float z[3][3] = {{1.0f,0.0f,0.0f},{0.0f,1.0f,0.0f},{0.0f,0.0f,1.0f}};
  const float eps = 5.9604644775390625e-08f;
  const float eps2 = 3.5527136788005009e-15f;
  const float safmin = 1.1754943508222875e-38f;
  int nmaxit = 90, jtot = 0;
  int l1 = 0;
  int l, m, lend, lsv, lendsv;
  float p, g, r, c, s, f, b_, rt1, rt2, tst;
  float wc[2], wsn[2];

outer_loop:
  if (l1 > 2) goto sorting;
  if (l1 > 0) e[l1 - 1] = 0.0f;
  {
    int mm;
    for (mm = l1; mm <= 1; ++mm) {
      tst = fabsf(e[mm]);
      if (tst == 0.0f) break;
      if (tst <= (sqrtf(fabsf(d[mm])) * sqrtf(fabsf(d[mm + 1]))) * eps) { e[mm] = 0.0f; break; }
    }
    m = (mm > 1) ? 2 : mm;
  }
  l = l1; lsv = l; lend = m; lendsv = lend; l1 = m + 1;
  if (lend == l) goto outer_loop;
  {
    float an = 0.0f;
    for (int i2 = l; i2 <= lend; ++i2) an = fmaxf(an, fabsf(d[i2]));
    for (int i2 = l; i2 < lend; ++i2) an = fmaxf(an, fabsf(e[i2]));
    if (an == 0.0f) goto outer_loop;
  }
  if (fabsf(d[lend]) < fabsf(d[l])) { lend = lsv; l = lendsv; }

  if (lend > l) {
ql40:
    if (l != lend) {
      for (m = l; m <= lend - 1; ++m) {
        tst = e[m] * e[m];
        if (tst <= (eps2 * fabsf(d[m])) * fabsf(d[m + 1]) + safmin) goto ql60;
      }
    }
    m = lend;
ql60:
    if (m < lend) e[m] = 0.0f;
    p = d[l];
    if (m == l) goto ql80;
    if (m == l + 1) {
      slaev2f(d[l], e[l], d[l + 1], &rt1, &rt2, &c, &s);
      for (int i2 = 0; i2 < 3; ++i2) {
        float temp = z[i2][l + 1];
        z[i2][l + 1] = c * temp - s * z[i2][l];
        z[i2][l]     = s * temp + c * z[i2][l];
      }
      d[l] = rt1; d[l + 1] = rt2; e[l] = 0.0f;
      l += 2;
      if (l <= lend) goto ql40;
      goto done140;
    }
    if (jtot == nmaxit) goto done140;
    jtot++;
    g = (d[l + 1] - p) / (2.0f * e[l]);
    r = slapy2f(g, 1.0f);
    g = d[m] - p + e[l] / (g + copysignf(r, g));
    s = 1.0f; c = 1.0f; p = 0.0f;
    for (int i2 = m - 1; i2 >= l; --i2) {
      f = s * e[i2]; b_ = c * e[i2];
      slartgf(g, f, &c, &s, &r);
      if (i2 != m - 1) e[i2 + 1] = r;
      g = d[i2 + 1] - p;
      r = (d[i2] - g) * s + 2.0f * c * b_;
      p = s * r;
      d[i2 + 1] = g + p;
      g = c * r - b_;
      wc[i2] = c; wsn[i2] = -s;
    }
    for (int j = m - 1; j >= l; --j) {
      float ct = wc[j], st = wsn[j];
      for (int i2 = 0; i2 < 3; ++i2) {
        float temp = z[i2][j + 1];
        z[i2][j + 1] = ct * temp - st * z[i2][j];
        z[i2][j]     = st * temp + ct * z[i2][j];
      }
    }
    d[l] -= p;
    e[l] = g;
    goto ql40;
ql80:
    d[l] = p;
    l += 1;
    if (l <= lend) goto ql40;
    goto done140;
  } else {
qr90:
    if (l != lend) {
      for (m = l; m >= lend + 1; --m) {
        tst = e[m - 1] * e[m - 1];
        if (tst <= (eps2 * fabsf(d[m])) * fabsf(d[m - 1]) + safmin) goto qr110;
      }
    }
    m = lend;
qr110:
    if (m > lend) e[m - 1] = 0.0f;
    p = d[l];
    if (m == l) goto qr130;
    if (m == l - 1) {
      slaev2f(d[l - 1], e[l - 1], d[l], &rt1, &rt2, &c, &s);
      for (int i2 = 0; i2 < 3; ++i2) {
        float temp = z[i2][l];
        z[i2][l]     = c * temp - s * z[i2][l - 1];
        z[i2][l - 1] = s * temp + c * z[i2][l - 1];
      }
      d[l - 1] = rt1; d[l] = rt2; e[l - 1] = 0.0f;
      l -= 2;
      if (l >= lend) goto qr90;
      goto done140;
    }
    if (jtot == nmaxit) goto done140;
    jtot++;
    g = (d[l - 1] - p) / (2.0f * e[l - 1]);
    r = slapy2f(g, 1.0f);
    g = d[m] - p + e[l - 1] / (g + copysignf(r, g));
    s = 1.0f; c = 1.0f; p = 0.0f;
    for (int i2 = m; i2 <= l - 1; ++i2) {
      f = s * e[i2]; b_ = c * e[i2];
      slartgf(g, f, &c, &s, &r);
      if (i2 != m) e[i2 - 1] = r;
      g = d[i2] - p;
      r = (d[i2 + 1] - g) * s + 2.0f * c * b_;
      p = s * r;
      d[i2] = g + p;
      g = c * r - b_;
      wc[i2] = c; wsn[i2] = s;
    }
    for (int j = m; j <= l - 1; ++j) {
      float ct = wc[j], st = wsn[j];
      for (int i2 = 0; i2 < 3; ++i2) {
        float temp = z[i2][j + 1];
        z[i2][j + 1] = ct * temp - st * z[i2][j];
        z[i2][j]     = st * temp + ct * z[i2][j];
      }
    }
    d[l] -= p;
    e[l - 1] = g;
    goto qr90;
qr130:
    d[l] = p;
    l -= 1;
    if (l >= lend) goto qr90;
    goto done140;
  }
done140:
  if (jtot < nmaxit) goto outer_loop;
sorting:
  for (int ii = 1; ii <= 2; ++ii) {
    int i_ = ii - 1, k = i_;
    p = d[i_];
    for (int j = ii; j <= 2; ++j) if (d[j] < p) { k = j; p = d[j]; }
    if (k != i_) {
      d[k] = d[i_]; d[i_] = p;
      for (int i2 = 0; i2 < 3; ++i2) { float tz = z[i2][i_]; z[i2][i_] = z[i2][k]; z[i2][k] = tz; }
    }
  }
  {
    float z10 = z[1][0], z20 = z[2][0];
    float sum = z10 + v2 * z20;
    evec[0] = z[0][0];
    evec[1] = z10 - tau * sum;
    evec[2] = z20 - tau * sum * v2;
  }
}

// ======================================================================
// Kernel 0: prep — pack xyz(+|p|^2) as float4, transpose w1/w2, zero stats
// ======================================================================
__global__ __launch_bounds__(256) void prep_kernel(const float* __restrict__ xyz,
                                                   const float* __restrict__ w1,
                                                   const float* __restrict__ w2,
                                                   float4* __restrict__ xyz4,
                                                   float* __restrict__ w1t,
                                                   float* __restrict__ w2t,
                                                   float* __restrict__ stats) {
  int idx = blockIdx.x * 256 + threadIdx.x;
  if (idx < BATCH * N_PTS) {
    float x = xyz[idx * 3], y = xyz[idx * 3 + 1], zz = xyz[idx * 3 + 2];
    float sq = fmaf(zz, zz, fmaf(y, y, x * x));
    xyz4[idx] = make_float4(x, y, zz, sq);
  }
  if (idx < 132 * CH) {
    int cc = idx >> 7, o = idx & 127;
    w1t[idx] = (cc < 131) ? w1[o * 131 + cc] : 0.0f;
  }
  if (idx < CH * CH) {
    int cc = idx >> 7, o = idx & 127;
    w2t[idx] = w2[o * CH + cc];
  }
  if (idx < 256) stats[idx] = 0.0f;
}

__device__ __forceinline__ float qdist(const float4 qv, const float4 cv) {
  float dot = fmaf(qv.x, cv.x, fmaf(qv.y, cv.y, qv.z * cv.z));
  return fmaf(-2.0f, dot, qv.w + cv.w);
}

__device__ __forceinline__ unsigned int distbits(float dist) {
  unsigned int du = __float_as_uint(dist);
  return (du & 0x80000000u) ? ~du : (du | 0x80000000u);
}

// ======================================================================
// Kernel 1: exact 20-NN, two index-chunked scans (R4 structure).
// Block: 512 thr = 8 waves; 64 queries (lane=query); wave w scans chunk
// [1024w,1024w+1024).
//  P1: per-(wave,query) exact 3-smallest (sorted c0<=c1<=c2) -> LDS.
//  Tq: 20th smallest of the 24 chunk-top-3 values (5-largest descending
//      insert network over 24) -> >=20 distinct cands <= Tq -> exact bound
//      (tighter than R4's max-of-3rds; rank(Tq)~30, P(>CAP=56)~1e-3).
//  P2: collect dist<=Tq into per-query LDS list (CAP=56; 30KB -> 4 blk/CU).
//  P3: 8-lane selection (R4-proven). Overflow: parallel register fallback
//      (8 subs x 1024-pt chunk top-20 + shuffle merge) — no serial tail.
// ======================================================================
__global__ __launch_bounds__(512) void knn_select_kernel(const float4* __restrict__ xyz4,
                                                         unsigned short* __restrict__ nidx) {
  __shared__ unsigned long long lst[64 * (CAP + 2)];   // 29696 B
  __shared__ float bnd3[24 * 64];                      // [w*3+k][l], 6144 B
  __shared__ unsigned int qcnt[64];
  __shared__ unsigned int qover[64];

  const int t = threadIdx.x;
  const int w = t >> 6, l = t & 63;
  const int batch = blockIdx.x >> 7;               // 128 blocks per batch
  const int q0 = (blockIdx.x & 127) << 6;          // 64 queries per block
  const float4* __restrict__ xb = xyz4 + batch * N_PTS;
  const float4 qv = xb[q0 + l];

  if (t < 64) { qcnt[t] = 0; qover[t] = 0; }

  const int base = __builtin_amdgcn_readfirstlane(w * 1024);

  // ---- Phase 1: exact 3-smallest of this wave's chunk (sorted) ----
  float c0 = INFINITY, c1 = INFINITY, c2 = INFINITY;
#pragma unroll 8
  for (int i = 0; i < 1024; ++i) {
    float4 cv = xb[base + i];
    float dist = qdist(qv, cv);
    float t0 = fmaxf(c0, dist); c0 = fminf(c0, dist);
    float t1 = fmaxf(c1, t0);   c1 = fminf(c1, t0);
    c2 = fminf(c2, t1);
  }
  bnd3[(w * 3 + 0) * 64 + l] = c0;
  bnd3[(w * 3 + 1) * 64 + l] = c1;
  bnd3[(w * 3 + 2) * 64 + l] = c2;
  __syncthreads();

  // ---- Tq = 20th smallest of 24 = 5th largest (descending 5-net) ----
  float m0 = -INFINITY, m1 = -INFINITY, m2 = -INFINITY, m3 = -INFINITY, m4 = -INFINITY;
#pragma unroll
  for (int k = 0; k < 24; ++k) {
    float v = bnd3[k * 64 + l];
    float u0 = fminf(m0, v);  m0 = fmaxf(m0, v);
    float u1 = fminf(m1, u0); m1 = fmaxf(m1, u0);
    float u2 = fminf(m2, u1); m2 = fmaxf(m2, u1);
    float u3 = fminf(m3, u2); m3 = fmaxf(m3, u2);
    m4 = fmaxf(m4, u3);
  }
  const float Tq = m4;

  // ---- Phase 2: collect ----
#pragma unroll 4
  for (int i = 0; i < 1024; ++i) {
    float4 cv = xb[base + i];
    float dist = qdist(qv, cv);
    if (dist <= Tq) {
      unsigned long long key = ((unsigned long long)distbits(dist) << 32)
                             | (unsigned int)(base + i);
      unsigned int pos = atomicAdd(&qcnt[l], 1u);
      if (pos < CAP) lst[l * (CAP + 2) + pos] = key;
      else qover[l] = 1u;
    }
  }
  __syncthreads();

  // ---- Phase 3: top-20 (8 lanes per query) ----
  const int qg = t >> 3, sub = t & 7;
  unsigned short* oq = nidx + ((size_t)(batch * N_PTS + q0 + qg)) * KNN;

  if (qover[qg]) {
    // parallel register fallback: 8 subs x 1024-pt index chunks
    const float4 qgv = xb[q0 + qg];
    unsigned long long best[KNN];
#pragma unroll
    for (int j = 0; j < KNN; ++j) best[j] = ~0ULL;
    const int pb = sub * 1024;
    for (int m = pb; m < pb + 1024; ++m) {
      float dist = qdist(qgv, xb[m]);
      unsigned long long pk = ((unsigned long long)distbits(dist) << 32)
                            | (unsigned int)m;
      if (pk < best[KNN - 1]) {
        best[KNN - 1] = pk;
#pragma unroll
        for (int j = KNN - 1; j > 0; --j) {
          unsigned long long xx = best[j - 1], yy = best[j];
          bool sw = yy < xx;
          best[j - 1] = sw ? yy : xx;
          best[j]     = sw ? xx : yy;
        }
      }
    }
    // 8-way sorted-list merge via shuffles (global top-20 = merge of chunk top-20s)
    for (int rr = 0; rr < KNN; ++rr) {
      unsigned long long b = best[0]; int wl = sub;
#pragma unroll
      for (int mm = 1; mm < 8; mm <<= 1) {
        unsigned long long ob = __shfl_xor(b, mm, 64);
        int owl = __shfl_xor(wl, mm, 64);
        if (ob < b) { b = ob; wl = owl; }
      }
      if (wl == sub) {
#pragma unroll
        for (int j = 0; j < KNN - 1; ++j) best[j] = best[j + 1];
        best[KNN - 1] = ~0ULL;
      }
      if (sub == 0) oq[rr] = (unsigned short)(b & 0xffffu);
    }
  } else {
    unsigned int n = qcnt[qg];
    for (int rr = 0; rr < KNN; ++rr) {
      unsigned long long best = ~0ULL; int bslot = 0;
      for (unsigned int s2 = sub; s2 < n; s2 += 8) {
        unsigned long long v = lst[qg * (CAP + 2) + s2];
        if (v < best) { best = v; bslot = (int)s2; }
      }
#pragma unroll
      for (int mm = 1; mm < 8; mm <<= 1) {
        unsigned long long ob = __shfl_xor(best, mm, 64);
        int obs = __shfl_xor(bslot, mm, 64);
        if (ob < best) { best = ob; bslot = obs; }
      }
      if ((bslot & 7) == sub) lst[qg * (CAP + 2) + bslot] = ~0ULL;
      if (sub == 0) oq[rr] = (unsigned short)(best & 0xffffu);
    }
  }
}

// ======================================================================
// Kernel 2: covariance (sorted order) + eigh -> normals
// ======================================================================
__global__ __launch_bounds__(256) void normals_kernel(const float4* __restrict__ xyz4,
                                                      const unsigned short* __restrict__ nidx,
                                                      float4* __restrict__ nrm4) {
  int gid = blockIdx.x * 256 + threadIdx.x;
  int batch = gid >> 13, q = gid & (N_PTS - 1);
  const float4* __restrict__ xb = xyz4 + batch * N_PTS;
  const float4 qv = xb[q];
  const unsigned short* iq = nidx + (size_t)gid * KNN;
  float c00, c01, c02, c11, c12, c22;
  {
#pragma clang fp contract(off)
    c00 = 0.f; c01 = 0.f; c02 = 0.f; c11 = 0.f; c12 = 0.f; c22 = 0.f;
    for (int j = 0; j < KNN; ++j) {
      float4 pv = xb[iq[j]];
      float dx = pv.x - qv.x, dy = pv.y - qv.y, dz = pv.z - qv.z;
      c00 = c00 + dx * dx; c01 = c01 + dx * dy; c02 = c02 + dx * dz;
      c11 = c11 + dy * dy; c12 = c12 + dy * dz; c22 = c22 + dz * dz;
    }
  }
  float ev[3];
  eigh3_smallest(c00, c01, c02, c11, c12, c22, ev);
  nrm4[gid] = make_float4(ev[0], ev[1], ev[2], 0.0f);
}

// ======================================================================
// Kernel 3: GEMM1 + BN stats
// ======================================================================
__global__ __launch_bounds__(256) void gemm1_stats_kernel(const float* __restrict__ x,
                                                          const float4* __restrict__ nrm4,
                                                          const float* __restrict__ w1t,
                                                          const float* __restrict__ b1,
                                                          float* __restrict__ sums,
                                                          float* __restrict__ sumsq) {
  __shared__ float lds[64 * 134];
  const int t = threadIdx.x;
  const int b = blockIdx.x >> 7;
  const int n0 = (blockIdx.x & 127) << 6;
  for (int idx = t; idx < CH * 64; idx += 256) {
    int cc = idx >> 6, nl = idx & 63;
    lds[nl * 134 + cc] = x[((size_t)(b * CH + cc)) * N_PTS + n0 + nl];
  }
  if (t < 64) {
    float4 nv = nrm4[b * N_PTS + n0 + t];
    lds[t * 134 + 128] = nv.x; lds[t * 134 + 129] = nv.y;
    lds[t * 134 + 130] = nv.z; lds[t * 134 + 131] = 0.0f;
  }
  __syncthreads();

  const int og = __builtin_amdgcn_readfirstlane(t >> 6);
  const int nl = t & 63;
  float acc[32];
#pragma unroll
  for (int k = 0; k < 32; ++k) acc[k] = b1[og * 32 + k];
  for (int c2 = 0; c2 < 66; ++c2) {
    float2 xv = *(const float2*)&lds[nl * 134 + 2 * c2];
    const float* wr0 = w1t + (2 * c2) * CH + og * 32;
    const float* wr1 = wr0 + CH;
#pragma unroll
    for (int k = 0; k < 32; ++k) acc[k] = fmaf(wr0[k], xv.x, acc[k]);
#pragma unroll
    for (int k = 0; k < 32; ++k) acc[k] = fmaf(wr1[k], xv.y, acc[k]);
  }
  __syncthreads();
#pragma unroll
  for (int k2 = 0; k2 < 16; ++k2)
    *(float2*)&lds[nl * 134 + og * 32 + 2 * k2] = make_float2(acc[2 * k2], acc[2 * k2 + 1]);
  __syncthreads();
  {
    int cc = t & 127, hf = t >> 7;
    float sm = 0.f, sq = 0.f;
    for (int rr = hf * 32; rr < hf * 32 + 32; ++rr) {
      float v = lds[rr * 134 + cc];
      sm += v; sq = fmaf(v, v, sq);
    }
    atomicAdd(&sums[cc], sm);
    atomicAdd(&sumsq[cc], sq);
  }
}

// ======================================================================
// Kernel 4: finalize BN scale/shift
// ======================================================================
__global__ void bn_finalize_kernel(const float* __restrict__ sums, const float* __restrict__ sumsq,
                                   const float* __restrict__ gamma, const float* __restrict__ beta,
                                   float* __restrict__ scale, float* __restrict__ shift) {
  int c = threadIdx.x;
  if (c < CH) {
    const double cnt = (double)(BATCH * N_PTS);
    double mean = (double)sums[c] / cnt;
    double var = (double)sumsq[c] / cnt - mean * mean;
    double inv = 1.0 / sqrt(var + 1e-5);
    double sc = (double)gamma[c] * inv;
    scale[c] = (float)sc;
    shift[c] = (float)((double)beta[c] - mean * sc);
  }
}

// ======================================================================
// Kernel 5: fused GEMM1 (recompute) + BN + ReLU + GEMM2 -> out
// ======================================================================
__global__ __launch_bounds__(256) void fused_out_kernel(const float* __restrict__ x,
                                                        const float4* __restrict__ nrm4,
                                                        const float* __restrict__ w1t,
                                                        const float* __restrict__ b1,
                                                        const float* __restrict__ w2t,
                                                        const float* __restrict__ b2,
                                                        const float* __restrict__ scale,
                                                        const float* __restrict__ shift,
                                                        float* __restrict__ out) {
  __shared__ float lds[64 * 134];
  const int t = threadIdx.x;
  const int b = blockIdx.x >> 7;
  const int n0 = (blockIdx.x & 127) << 6;
  for (int idx = t; idx < CH * 64; idx += 256) {
    int cc = idx >> 6, nl = idx & 63;
    lds[nl * 134 + cc] = x[((size_t)(b * CH + cc)) * N_PTS + n0 + nl];
  }
  if (t < 64) {
    float4 nv = nrm4[b * N_PTS + n0 + t];
    lds[t * 134 + 128] = nv.x; lds[t * 134 + 129] = nv.y;
    lds[t * 134 + 130] = nv.z; lds[t * 134 + 131] = 0.0f;
  }
  __syncthreads();

  const int og = __builtin_amdgcn_readfirstlane(t >> 6);
  const int nl = t & 63;
  float acc[32];
#pragma unroll
  for (int k = 0; k < 32; ++k) acc[k] = b1[og * 32 + k];
  for (int c2 = 0; c2 < 66; ++c2) {
    float2 xv = *(const float2*)&lds[nl * 134 + 2 * c2];
    const float* wr0 = w1t + (2 * c2) * CH + og * 32;
    const float* wr1 = wr0 + CH;
#pragma unroll
    for (int k = 0; k < 32; ++k) acc[k] = fmaf(wr0[k], xv.x, acc[k]);
#pragma unroll
    for (int k = 0; k < 32; ++k) acc[k] = fmaf(wr1[k], xv.y, acc[k]);
  }
#pragma unroll
  for (int k = 0; k < 32; ++k) {
    float sc = scale[og * 32 + k], sh = shift[og * 32 + k];
    acc[k] = fmaxf(fmaf(acc[k], sc, sh), 0.0f);
  }
  __syncthreads();
#pragma unroll
  for (int k2 = 0; k2 < 16; ++k2)
    *(float2*)&lds[nl * 134 + og * 32 + 2 * k2] = make_float2(acc[2 * k2], acc[2 * k2 + 1]);
  __syncthreads();

  float acc2[32];
#pragma unroll
  for (int k = 0; k < 32; ++k) acc2[k] = b2[og * 32 + k];
  for (int c2 = 0; c2 < 64; ++c2) {
    float2 hv = *(const float2*)&lds[nl * 134 + 2 * c2];
    const float* wr0 = w2t + (2 * c2) * CH + og * 32;
    const float* wr1 = wr0 + CH;
#pragma unroll
    for (int k = 0; k < 32; ++k) acc2[k] = fmaf(wr0[k], hv.x, acc2[k]);
#pragma unroll
    for (int k = 0; k < 32; ++k) acc2[k] = fmaf(wr1[k], hv.y, acc2[k]);
  }
#pragma unroll
  for (int k = 0; k < 32; ++k) {
    int o = og * 32 + k;
    out[((size_t)(b * CH + o)) * N_PTS + n0 + nl] = acc2[k];
  }
}

// ======================================================================
extern "C" void kernel_launch(void* const* d_in, const int* in_sizes, int n_in,
                              void* d_out, int out_size, void* d_ws, size_t ws_size,
                              hipStream_t stream) {
  const float* x     = (const float*)d_in[0];
  const float* xyz   = (const float*)d_in[1];
  const float* w1    = (const float*)d_in[2];
  const float* b1    = (const float*)d_in[3];
  const float* gamma = (const float*)d_in[4];
  const float* beta  = (const float*)d_in[5];
  const float* w2    = (const float*)d_in[6];
  const float* b2    = (const float*)d_in[7];
  float* out = (float*)d_out;

  float* W = (float*)d_ws;
  float4* xyz4 = (float4*)W;                         // 131072 floats
  float4* nrm4 = (float4*)(W + 131072);              // 131072 floats
  float* w1t   = W + 262144;                         // 132*128 = 16896
  float* w2t   = W + 279040;                         // 128*128 = 16384
  float* stats = W + 295424;                         // sums[128] | sumsq[128]
  float* scale = W + 295680;                         // 128
  float* shift = W + 295808;                         // 128
  unsigned short* nidx = (unsigned short*)(W + 295936);  // 32768*20 u16

  prep_kernel<<<128, 256, 0, stream>>>(xyz, w1, w2, xyz4, w1t, w2t, stats);
  knn_select_kernel<<<BATCH * N_PTS / 64, 512, 0, stream>>>(xyz4, nidx);
  normals_kernel<<<BATCH * N_PTS / 256, 256, 0, stream>>>(xyz4, nidx, nrm4);
  gemm1_stats_kernel<<<BATCH * N_PTS / 64, 256, 0, stream>>>(x, nrm4, w1t, b1, stats, stats + 128);
  bn_finalize_kernel<<<1, 128, 0, stream>>>(stats, stats + 128, gamma, beta, scale, shift);
  fused_out_kernel<<<BATCH * N_PTS / 64, 256, 0, stream>>>(x, nrm4, w1t, b1, w2t, b2, scale, shift, out);
}